// Round 11
// baseline (400.031 us; speedup 1.0000x reference)
//
#include <hip/hip_runtime.h>
#include <hip/hip_bf16.h>
#include <math.h>

#define D      128
#define NID    16
#define H      4
#define CH     32
#define NLAYER 4
#define EPS    1e-5f
#define NEG    0.2f
#define LOG2E  1.442695040888963f

typedef __attribute__((ext_vector_type(8))) short short8;
typedef __attribute__((ext_vector_type(4))) float floatx4;
typedef _Float16 h2 __attribute__((ext_vector_type(2)));

__device__ __forceinline__ float2 bf2_to_f2(unsigned int u) {
    float2 r;
    unsigned int lo = u << 16;
    unsigned int hi = u & 0xffff0000u;
    r.x = __uint_as_float(lo);
    r.y = __uint_as_float(hi);
    return r;
}

__device__ __forceinline__ unsigned short f2bf(float f) {
    __hip_bfloat16 h = __float2bfloat16(f);
    return *reinterpret_cast<unsigned short*>(&h);
}

__device__ __forceinline__ unsigned short f2h(float f) {
    _Float16 h = (_Float16)f;
    unsigned short u;
    __builtin_memcpy(&u, &h, 2);
    return u;
}

__device__ __forceinline__ h2 u2h2(unsigned int u) {
    h2 v;
    __builtin_memcpy(&v, &u, 4);
    return v;
}

// ---------------------------------------------------------------------------
// CSR build pieces. Launch-DAG restructure (round 11): count_deg folded into
// setup (deg zeroed by memset; self-loop +1 folded into scan_blocks);
// scatter folded into the layer-0 GEMM dispatch. 13 -> 12 dispatches,
// ~20us of serial CSR time now overlaps setup/GEMM0.
// ---------------------------------------------------------------------------

__global__ __launch_bounds__(256) void scan_blocks_kernel(const int* __restrict__ deg, int* __restrict__ offs,
                                                          int* __restrict__ bsum, int n) {
    __shared__ int sw[8];
    int t = threadIdx.x;
    int i = blockIdx.x * 256 + t;
    int v = (i < n) ? deg[i] + 1 : 0;   // +1 = self loop (deg holds in-degree only)
    int lane = t & 63, w = t >> 6;
    int x = v;
    #pragma unroll
    for (int off = 1; off < 64; off <<= 1) {
        int y = __shfl_up(x, off, 64);
        if (lane >= off) x += y;
    }
    if (lane == 63) sw[w] = x;
    __syncthreads();
    if (t == 0) {
        int s = 0;
        for (int k = 0; k < 4; ++k) { int tv = sw[k]; sw[k] = s; s += tv; }
        sw[4] = s;
    }
    __syncthreads();
    int excl = x - v + sw[w];
    if (i < n) offs[i] = excl;
    if (t == 255) bsum[blockIdx.x] = sw[4];
}

// fused: per-block local reduction of bsum[0..bid) + offset add + cursor init
__global__ __launch_bounds__(256) void scan_add_kernel(int* __restrict__ offs, const int* __restrict__ bsum,
                                                       int* __restrict__ cursor, int n, int nb, int total) {
    __shared__ int sw[8];
    __shared__ int sS;
    int t = threadIdx.x;
    int bid = blockIdx.x;
    int v = (t < bid && t < nb) ? bsum[t] : 0;
    int lane = t & 63, w = t >> 6;
    #pragma unroll
    for (int off = 32; off > 0; off >>= 1) v += __shfl_xor(v, off, 64);
    if (lane == 0) sw[w] = v;
    __syncthreads();
    if (t == 0) sS = sw[0] + sw[1] + sw[2] + sw[3];
    __syncthreads();
    int S = sS;
    int i = bid * 256 + t;
    if (i < n) {
        int o = offs[i] + S;
        offs[i] = o;
        cursor[i] = o;
    }
    if (i == 0) offs[n] = total;
}

// ---------------------------------------------------------------------------
// Fused setup: [0,nbEmbed) embed+proj+LN+ReLU -> bf16 x;
// [nbEmbed, +512) W->bf16 W^T; [then, nbE blocks] count_deg atomics
// (deg pre-zeroed by hipMemsetAsync; overlaps the embed/wt work).
// ---------------------------------------------------------------------------
__global__ __launch_bounds__(256) void setup_kernel(
    const int* __restrict__ types, const float* __restrict__ emb,
    const float* __restrict__ W, const float* __restrict__ b,
    const float* __restrict__ g, const float* __restrict__ beta,
    unsigned short* __restrict__ x,
    const float* __restrict__ Wl, const float* __restrict__ Wr,
    unsigned short* __restrict__ wt,
    const int* __restrict__ dsts, int* __restrict__ deg, int e,
    int n, int nbEmbed) {
    __shared__ float sW[NID * D];
    __shared__ float semb[3 * NID];
    int blk = blockIdx.x;
    int t = threadIdx.x;
    if (blk < nbEmbed) {
        for (int i = t; i < NID * D; i += 256) sW[i] = W[i];
        for (int i = t; i < 3 * NID; i += 256) semb[i] = emb[i];
        __syncthreads();
        int lane = t & 63, w = t >> 6;
        int node = blk * 4 + w;
        if (node >= n) return;
        int c0 = 2 * lane;
        int ty = types[node];
        const float* ev = &semb[ty * NID];
        float v0 = b[c0], v1 = b[c0 + 1];
        #pragma unroll
        for (int k = 0; k < NID; ++k) {
            float ek = ev[k];
            v0 = fmaf(ek, sW[k * D + c0], v0);
            v1 = fmaf(ek, sW[k * D + c0 + 1], v1);
        }
        float s = v0 + v1, sq = v0 * v0 + v1 * v1;
        #pragma unroll
        for (int off = 1; off < 64; off <<= 1) {
            s  += __shfl_xor(s, off, 64);
            sq += __shfl_xor(sq, off, 64);
        }
        float mu  = s * (1.0f / D);
        float var = sq * (1.0f / D) - mu * mu;
        float r   = rsqrtf(var + EPS);
        v0 = fmaxf((v0 - mu) * r * g[c0]     + beta[c0],     0.0f);
        v1 = fmaxf((v1 - mu) * r * g[c0 + 1] + beta[c0 + 1], 0.0f);
        unsigned int packed = (unsigned int)f2bf(v0) | ((unsigned int)f2bf(v1) << 16);
        *(unsigned int*)(x + (size_t)node * D + c0) = packed;
    } else if (blk < nbEmbed + 512) {
        int idx = (blk - nbEmbed) * 256 + t;   // L*2*D*D = 131072
        int k    = idx & (D - 1);
        int nrow = (idx >> 7) & (D - 1);
        int s    = (idx >> 14) & 1;
        int l    = idx >> 15;
        const float* Wm = s ? Wr : Wl;
        wt[idx] = f2bf(Wm[(size_t)l * D * D + (size_t)k * D + nrow]);
    } else {
        int i = (blk - nbEmbed - 512) * 256 + t;
        if (i < e) atomicAdd(&deg[dsts[i]], 1);   // count_deg (deg pre-zeroed)
    }
}

// ---------------------------------------------------------------------------
// Dual GEMM via bf16 MFMA; bf16 in, fp16 out. Layer 0 only: extra blocks
// past ntiles run the CSR scatter (independent work, hides its ~15us under
// the GEMM). All 16 B-fragments preloaded into registers at entry.
// ---------------------------------------------------------------------------
__global__ __launch_bounds__(256) void dual_gemm_mfma_kernel(
    const unsigned short* __restrict__ x, const unsigned short* __restrict__ wt,
    const float* __restrict__ bl, const float* __restrict__ br,
    unsigned short* __restrict__ xl, unsigned short* __restrict__ xr, int n,
    int ntiles,
    const int* __restrict__ srcs, const int* __restrict__ dsts, int e,
    int* __restrict__ cursor, int* __restrict__ csr_src) {
    __shared__ __align__(16) unsigned short sa[64 * 136];
    int t = threadIdx.x;
    if (blockIdx.x >= ntiles) {
        // ---- scatter blocks (layer 0 only): dst-sorted CSR, self loops ----
        int i = (blockIdx.x - ntiles) * 256 + t;
        if (i < e) {
            int pos = atomicAdd(&cursor[dsts[i]], 1);
            csr_src[pos] = srcs[i];
        } else if (i < e + n) {
            int node = i - e;
            int pos = atomicAdd(&cursor[node], 1);
            csr_src[pos] = node;  // self loop
        }
        return;
    }
    int nbase = blockIdx.x * 64;
    int rows = n - nbase; if (rows > 64) rows = 64;
    int lane = t & 63, w = t >> 6;
    int L = lane & 15, q = lane >> 4;
    int s  = w >> 1;          // 0: Wl, 1: Wr
    int n0 = (w & 1) * 64;    // col strip base within this matrix
    const unsigned short* wb = wt + ((size_t)s * D + n0) * D;
    // ---- preload all B fragments (independent L2 loads, overlap staging) ----
    short8 b[4][4];           // [kk][ni]
    #pragma unroll
    for (int kk = 0; kk < 4; ++kk)
        #pragma unroll
        for (int ni = 0; ni < 4; ++ni)
            b[kk][ni] = *(const short8*)(wb + (size_t)(ni * 16 + L) * D + kk * 32 + q * 8);
    // ---- stage bf16 x -> LDS (stride 136) ----
    {
        int r   = t >> 2;
        int seg = t & 3;                 // 32 ch = 64 B each
        uint4* drow = (uint4*)(sa + r * 136 + seg * 32);
        if (r < rows) {
            const uint4* srow = (const uint4*)(x + (size_t)(nbase + r) * D + seg * 32);
            drow[0] = srow[0]; drow[1] = srow[1]; drow[2] = srow[2]; drow[3] = srow[3];
        } else {
            uint4 z = make_uint4(0, 0, 0, 0);
            drow[0] = z; drow[1] = z; drow[2] = z; drow[3] = z;
        }
    }
    __syncthreads();
    floatx4 acc[4][4];
    #pragma unroll
    for (int mi = 0; mi < 4; ++mi)
        #pragma unroll
        for (int ni = 0; ni < 4; ++ni)
            acc[mi][ni] = (floatx4){0.0f, 0.0f, 0.0f, 0.0f};
    #pragma unroll
    for (int kk = 0; kk < 4; ++kk) {
        int ko = kk * 32 + q * 8;
        short8 a[4];
        #pragma unroll
        for (int mi = 0; mi < 4; ++mi)
            a[mi] = *(const short8*)(sa + (mi * 16 + L) * 136 + ko);
        #pragma unroll
        for (int mi = 0; mi < 4; ++mi)
            #pragma unroll
            for (int ni = 0; ni < 4; ++ni)
                acc[mi][ni] = __builtin_amdgcn_mfma_f32_16x16x32_bf16(a[mi], b[kk][ni], acc[mi][ni], 0, 0, 0);
    }
    // ---- epilogue via LDS: +bias, fp16, vectorized stores ----
    const float* bias = s ? br : bl;
    #pragma unroll 1
    for (int pass = 0; pass < 2; ++pass) {
        __syncthreads();
        if (s == pass) {
            #pragma unroll
            for (int ni = 0; ni < 4; ++ni) {
                int col = n0 + ni * 16 + L;
                float bv = bias[col];
                #pragma unroll
                for (int mi = 0; mi < 4; ++mi) {
                    #pragma unroll
                    for (int r = 0; r < 4; ++r) {
                        int row = mi * 16 + q * 4 + r;
                        sa[row * 136 + col] = f2h(acc[mi][ni][r] + bv);
                    }
                }
            }
        }
        __syncthreads();
        unsigned short* outp = pass ? xr : xl;
        #pragma unroll
        for (int c = 0; c < 4; ++c) {
            int chunk = c * 256 + t;        // 0..1023
            int row   = chunk >> 4;
            int off   = (chunk & 15) * 8;
            if (row < rows) {
                short8 v = *(const short8*)(sa + row * 136 + off);
                *(short8*)(outp + (size_t)(nbase + row) * D + off) = v;
            }
        }
    }
}

// ---------------------------------------------------------------------------
// Fused GATv2 aggregation, fp16 packed-math edge MLP + packed-f16 in-loop
// accumulator. att pre-scaled by log2(e) -> bare exp2f. Wave = 1 node;
// lane = (edge slot g = lane>>4) x (channel block l = lane&15, 8 ch) --
// coalesced. 2-deep gather pipeline. Now ~L3-gather-bound (~77MB L2-miss
// per dispatch at ~2.1-2.4 TB/s).
// NOTE (rounds 8/9): persistent-kernel fusion is NOT viable -- software
// grid barriers cost ~90-145us each at 720 blocks on gfx950.
// ---------------------------------------------------------------------------
__global__ __launch_bounds__(256) void gat_agg_kernel(
    const unsigned short* __restrict__ xl, const unsigned short* __restrict__ xr,
    const unsigned short* __restrict__ xin,
    const int* __restrict__ offs, const int* __restrict__ csr_src,
    const float* __restrict__ att,
    const float* __restrict__ gbias,
    const float* __restrict__ lng, const float* __restrict__ lnb,
    unsigned short* __restrict__ xout_bf, float* __restrict__ xout_f32, int n) {
    int t = threadIdx.x;
    int lane = t & 63, w = t >> 6;
    int node = blockIdx.x * 4 + w;
    if (node >= n) return;
    int g  = lane >> 4;       // edge slot 0..3
    int l  = lane & 15;       // channel block 0..15 (8 ch each)
    int cb = l * 8;
    h2 xr2[4], at2[4];
    {
        uint4 u = *(const uint4*)(xr + (size_t)node * D + cb);
        xr2[0] = u2h2(u.x); xr2[1] = u2h2(u.y); xr2[2] = u2h2(u.z); xr2[3] = u2h2(u.w);
        float4 t0 = *(const float4*)(att + cb);
        float4 t1 = *(const float4*)(att + cb + 4);
        // fold log2(e) into att: logit p is then in exp2 domain
        at2[0] = (h2){(_Float16)(t0.x * LOG2E), (_Float16)(t0.y * LOG2E)};
        at2[1] = (h2){(_Float16)(t0.z * LOG2E), (_Float16)(t0.w * LOG2E)};
        at2[2] = (h2){(_Float16)(t1.x * LOG2E), (_Float16)(t1.y * LOG2E)};
        at2[3] = (h2){(_Float16)(t1.z * LOG2E), (_Float16)(t1.w * LOG2E)};
    }
    h2 acch[4];
    #pragma unroll
    for (int i = 0; i < 4; ++i) acch[i] = (h2){(_Float16)0.0f, (_Float16)0.0f};
    float lsum = 0.0f;
    int s0 = offs[node], s1 = offs[node + 1];
    // ---- 2-deep pipeline prologue: idx(0), gather(0), idx(1), gather(1), idx(2)
    int j0 = s0 + g;
    bool val_c = j0 < s1;
    int src_c = csr_src[val_c ? j0 : s0];
    uint4 u_c = *(const uint4*)(xl + (size_t)src_c * D + cb);
    int j1 = j0 + 4;
    bool val_n = j1 < s1;
    int src_n = csr_src[val_n ? j1 : s0];
    uint4 u_n = *(const uint4*)(xl + (size_t)src_n * D + cb);
    int j2 = j0 + 8;
    bool val_2 = j2 < s1;
    int src_2 = csr_src[val_2 ? j2 : s0];
    for (int j = s0; j < s1; j += 4) {
        // issue gather(i+2)
        uint4 u_2 = *(const uint4*)(xl + (size_t)src_2 * D + cb);
        // issue idx(i+3)
        int j3 = j + 12 + g;
        bool val_3 = j3 < s1;
        int src_3 = csr_src[val_3 ? j3 : s0];
        // consume gather(i): packed f16 edge MLP
        h2 xv2[4];
        xv2[0] = u2h2(u_c.x); xv2[1] = u2h2(u_c.y); xv2[2] = u2h2(u_c.z); xv2[3] = u2h2(u_c.w);
        float p = 0.0f;
        #pragma unroll
        for (int i = 0; i < 4; ++i) {
            h2 e  = xv2[i] + xr2[i];
            h2 el = __builtin_elementwise_max(e, e * (_Float16)NEG);  // leaky_relu
            p = __builtin_amdgcn_fdot2(el, at2[i], p, false);
        }
        p += __shfl_xor(p, 1, 64);      // reduce over the head's 4 lanes
        p += __shfl_xor(p, 2, 64);
        float wgt = val_c ? exp2f(p) : 0.0f;   // att pre-scaled by log2e
        lsum += wgt;
        _Float16 wh = (_Float16)wgt;
        h2 w2 = {wh, wh};
        #pragma unroll
        for (int i = 0; i < 4; ++i) acch[i] += w2 * xv2[i];   // v_pk_fma_f16
        // shift pipeline
        u_c = u_n; u_n = u_2;
        val_c = val_n; val_n = val_2;
        val_2 = val_3; src_2 = src_3;
    }
    // widen to f32, then cross-group reduction (sum over the 4 edge slots)
    float acc[8];
    #pragma unroll
    for (int i = 0; i < 4; ++i) {
        acc[2 * i]     = (float)acch[i][0];
        acc[2 * i + 1] = (float)acch[i][1];
    }
    #pragma unroll
    for (int i = 0; i < 8; ++i) {
        acc[i] += __shfl_xor(acc[i], 16, 64);
        acc[i] += __shfl_xor(acc[i], 32, 64);
    }
    lsum += __shfl_xor(lsum, 16, 64);
    lsum += __shfl_xor(lsum, 32, 64);
    float inv = 1.0f / lsum;
    // bias + residual (bf16)
    float xi[8];
    {
        uint4 u = *(const uint4*)(xin + (size_t)node * D + cb);
        float2 a = bf2_to_f2(u.x), b = bf2_to_f2(u.y), c = bf2_to_f2(u.z), d = bf2_to_f2(u.w);
        xi[0]=a.x; xi[1]=a.y; xi[2]=b.x; xi[3]=b.y; xi[4]=c.x; xi[5]=c.y; xi[6]=d.x; xi[7]=d.y;
    }
    float4 gb0 = *(const float4*)(gbias + cb);
    float4 gb1 = *(const float4*)(gbias + cb + 4);
    float gb[8] = {gb0.x, gb0.y, gb0.z, gb0.w, gb1.x, gb1.y, gb1.z, gb1.w};
    float v[8];
    #pragma unroll
    for (int i = 0; i < 8; ++i) v[i] = fmaf(acc[i], inv, gb[i] + xi[i]);
    // LayerNorm over the 16 channel-block lanes
    float s = 0.0f, sq = 0.0f;
    #pragma unroll
    for (int i = 0; i < 8; ++i) { s += v[i]; sq = fmaf(v[i], v[i], sq); }
    #pragma unroll
    for (int off = 1; off < 16; off <<= 1) {
        s  += __shfl_xor(s, off, 64);
        sq += __shfl_xor(sq, off, 64);
    }
    float mu  = s * (1.0f / D);
    float var = sq * (1.0f / D) - mu * mu;
    float r   = rsqrtf(var + EPS);
    float4 lg0 = *(const float4*)(lng + cb);
    float4 lg1 = *(const float4*)(lng + cb + 4);
    float4 lb0 = *(const float4*)(lnb + cb);
    float4 lb1 = *(const float4*)(lnb + cb + 4);
    float lg[8] = {lg0.x, lg0.y, lg0.z, lg0.w, lg1.x, lg1.y, lg1.z, lg1.w};
    float lb[8] = {lb0.x, lb0.y, lb0.z, lb0.w, lb1.x, lb1.y, lb1.z, lb1.w};
    float o[8];
    #pragma unroll
    for (int i = 0; i < 8; ++i) o[i] = fmaxf((v[i] - mu) * r * lg[i] + lb[i], 0.0f);
    if (g == 0) {
        if (xout_f32) {
            *(float4*)(xout_f32 + (size_t)node * D + cb)     = make_float4(o[0], o[1], o[2], o[3]);
            *(float4*)(xout_f32 + (size_t)node * D + cb + 4) = make_float4(o[4], o[5], o[6], o[7]);
        } else {
            unsigned int p0 = (unsigned int)f2bf(o[0]) | ((unsigned int)f2bf(o[1]) << 16);
            unsigned int p1 = (unsigned int)f2bf(o[2]) | ((unsigned int)f2bf(o[3]) << 16);
            unsigned int p2 = (unsigned int)f2bf(o[4]) | ((unsigned int)f2bf(o[5]) << 16);
            unsigned int p3 = (unsigned int)f2bf(o[6]) | ((unsigned int)f2bf(o[7]) << 16);
            *(uint4*)(xout_bf + (size_t)node * D + cb) = make_uint4(p0, p1, p2, p3);
        }
    }
}

// ---------------------------------------------------------------------------
extern "C" void kernel_launch(void* const* d_in, const int* in_sizes, int n_in,
                              void* d_out, int out_size, void* d_ws, size_t ws_size,
                              hipStream_t stream) {
    const int*   node_types = (const int*)d_in[0];
    const int*   edge_index = (const int*)d_in[1];
    const float* emb        = (const float*)d_in[2];
    const float* projW      = (const float*)d_in[3];
    const float* projb      = (const float*)d_in[4];
    const float* projg      = (const float*)d_in[5];
    const float* projbeta   = (const float*)d_in[6];
    const float* Wl         = (const float*)d_in[7];
    const float* bl         = (const float*)d_in[8];
    const float* Wr         = (const float*)d_in[9];
    const float* br         = (const float*)d_in[10];
    const float* att        = (const float*)d_in[11];
    const float* gbias      = (const float*)d_in[12];
    const float* lng        = (const float*)d_in[13];
    const float* lnb        = (const float*)d_in[14];
    float* out = (float*)d_out;

    int n = in_sizes[0];
    int e = in_sizes[1] / 2;
    const int* srcs = edge_index;
    const int* dsts = edge_index + e;

    char* p = (char*)d_ws;
    auto carve = [&](size_t bytes) {
        char* q = p;
        p += (bytes + 255) & ~(size_t)255;
        return q;
    };
    int*   deg     = (int*)carve((size_t)n * 4);
    int*   offs    = (int*)carve((size_t)(n + 1) * 4);
    int*   cursor  = (int*)carve((size_t)n * 4);
    int*   bsum    = (int*)carve(256 * 4);
    int*   csr_src = (int*)carve((size_t)(e + n) * 4);
    unsigned short* xbuf = (unsigned short*)carve((size_t)n * D * 2);
    unsigned short* xlb  = (unsigned short*)carve((size_t)n * D * 2);
    unsigned short* xrb  = (unsigned short*)carve((size_t)n * D * 2);
    unsigned short* wt   = (unsigned short*)carve((size_t)NLAYER * 2 * D * D * 2);

    int nb = (n + 255) / 256;        // 196 for N=50000
    int nbEmbed = (n + 3) / 4;       // 12500
    int nbE = (e + 255) / 256;       // 2344 count blocks
    int ntiles = (n + 63) / 64;      // 782 GEMM tiles
    int nscat  = (e + n + 255) / 256;// 2540 scatter blocks

    // ---- deg := 0 (count_deg now runs inside setup; self loop folded into scan)
    hipMemsetAsync(deg, 0, (size_t)n * 4, stream);

    // ---- fused setup: embed/proj/LN -> bf16 x ; W -> bf16 W^T ; count_deg ----
    setup_kernel<<<nbEmbed + 512 + nbE, 256, 0, stream>>>(
        node_types, emb, projW, projb, projg, projbeta, xbuf,
        Wl, Wr, wt, dsts, deg, e, n, nbEmbed);

    // ---- CSR offsets ----
    scan_blocks_kernel<<<nb, 256, 0, stream>>>(deg, offs, bsum, n);
    scan_add_kernel<<<nb, 256, 0, stream>>>(offs, bsum, cursor, n, nb, e + n);

    // ---- 4 GATv2 layers; layer-0 GEMM dispatch also runs the CSR scatter ----
    for (int layer = 0; layer < NLAYER; ++layer) {
        int extra = (layer == 0) ? nscat : 0;
        dual_gemm_mfma_kernel<<<ntiles + extra, 256, 0, stream>>>(
            xbuf, wt + (size_t)layer * 2 * D * D,
            bl + (size_t)layer * D, br + (size_t)layer * D, xlb, xrb, n,
            ntiles, srcs, dsts, e, cursor, csr_src);
        bool last = (layer == NLAYER - 1);
        gat_agg_kernel<<<(n + 3) / 4, 256, 0, stream>>>(
            xlb, xrb, xbuf, offs, csr_src,
            att + (size_t)layer * H * CH, gbias + (size_t)layer * D,
            lng + (size_t)layer * D, lnb + (size_t)layer * D,
            last ? (unsigned short*)nullptr : xbuf, last ? out : (float*)nullptr, n);
    }
}

// Round 12
// 393.739 us; speedup vs baseline: 1.0160x; 1.0160x over previous
//
#include <hip/hip_runtime.h>
#include <hip/hip_bf16.h>
#include <math.h>

#define D      128
#define NID    16
#define H      4
#define CH     32
#define NLAYER 4
#define EPS    1e-5f
#define NEG    0.2f
#define LOG2E  1.442695040888963f

typedef __attribute__((ext_vector_type(8))) short short8;
typedef __attribute__((ext_vector_type(4))) float floatx4;
typedef _Float16 h2 __attribute__((ext_vector_type(2)));
typedef float fx2 __attribute__((ext_vector_type(2)));

__device__ __forceinline__ float2 bf2_to_f2(unsigned int u) {
    float2 r;
    unsigned int lo = u << 16;
    unsigned int hi = u & 0xffff0000u;
    r.x = __uint_as_float(lo);
    r.y = __uint_as_float(hi);
    return r;
}

__device__ __forceinline__ unsigned short f2bf(float f) {
    __hip_bfloat16 h = __float2bfloat16(f);
    return *reinterpret_cast<unsigned short*>(&h);
}

__device__ __forceinline__ unsigned short f2h(float f) {
    _Float16 h = (_Float16)f;
    unsigned short u;
    __builtin_memcpy(&u, &h, 2);
    return u;
}

__device__ __forceinline__ h2 u2h2(unsigned int u) {
    h2 v;
    __builtin_memcpy(&v, &u, 4);
    return v;
}

// pack 2 f32 -> h2 via v_cvt_pkrtz_f16_f32 (1 inst); memcpy dodges the
// __fp16/_Float16 vector-type mismatch between builtin ret and h2.
__device__ __forceinline__ h2 pkrtz(float a, float b) {
    auto r = __builtin_amdgcn_cvt_pkrtz(a, b);
    h2 out;
    __builtin_memcpy(&out, &r, 4);
    return out;
}

// fp8 e4m3 (OCP on gfx950) encode of one float -> byte
__device__ __forceinline__ unsigned char f2fp8(float v) {
    int pk = __builtin_amdgcn_cvt_pk_fp8_f32(v, v, 0, false);
    return (unsigned char)(pk & 0xff);
}

// decode 4 fp8 bytes (one dword) -> 2x h2
__device__ __forceinline__ void fp8x4_to_h2x2(unsigned int w, h2* out) {
    fx2 f0 = __builtin_amdgcn_cvt_pk_f32_fp8((int)w, false);
    fx2 f1 = __builtin_amdgcn_cvt_pk_f32_fp8((int)w, true);
    out[0] = pkrtz(f0[0], f0[1]);
    out[1] = pkrtz(f1[0], f1[1]);
}

// ---------------------------------------------------------------------------
// CSR build pieces. count_deg folded into setup (deg zeroed by memset;
// self-loop +1 folded into scan_blocks); scatter folded into the layer-0
// GEMM dispatch (measured r11: scatter is ~45-60us dominated by random-write
// line amplification, ~41MB of WRITE per build -- unavoidable at this graph).
// ---------------------------------------------------------------------------

__global__ __launch_bounds__(256) void scan_blocks_kernel(const int* __restrict__ deg, int* __restrict__ offs,
                                                          int* __restrict__ bsum, int n) {
    __shared__ int sw[8];
    int t = threadIdx.x;
    int i = blockIdx.x * 256 + t;
    int v = (i < n) ? deg[i] + 1 : 0;   // +1 = self loop (deg holds in-degree only)
    int lane = t & 63, w = t >> 6;
    int x = v;
    #pragma unroll
    for (int off = 1; off < 64; off <<= 1) {
        int y = __shfl_up(x, off, 64);
        if (lane >= off) x += y;
    }
    if (lane == 63) sw[w] = x;
    __syncthreads();
    if (t == 0) {
        int s = 0;
        for (int k = 0; k < 4; ++k) { int tv = sw[k]; sw[k] = s; s += tv; }
        sw[4] = s;
    }
    __syncthreads();
    int excl = x - v + sw[w];
    if (i < n) offs[i] = excl;
    if (t == 255) bsum[blockIdx.x] = sw[4];
}

__global__ __launch_bounds__(256) void scan_add_kernel(int* __restrict__ offs, const int* __restrict__ bsum,
                                                       int* __restrict__ cursor, int n, int nb, int total) {
    __shared__ int sw[8];
    __shared__ int sS;
    int t = threadIdx.x;
    int bid = blockIdx.x;
    int v = (t < bid && t < nb) ? bsum[t] : 0;
    int lane = t & 63, w = t >> 6;
    #pragma unroll
    for (int off = 32; off > 0; off >>= 1) v += __shfl_xor(v, off, 64);
    if (lane == 0) sw[w] = v;
    __syncthreads();
    if (t == 0) sS = sw[0] + sw[1] + sw[2] + sw[3];
    __syncthreads();
    int S = sS;
    int i = bid * 256 + t;
    if (i < n) {
        int o = offs[i] + S;
        offs[i] = o;
        cursor[i] = o;
    }
    if (i == 0) offs[n] = total;
}

// ---------------------------------------------------------------------------
// Fused setup: embed+proj+LN+ReLU -> bf16 x; W->bf16 W^T; count_deg atomics.
// ---------------------------------------------------------------------------
__global__ __launch_bounds__(256) void setup_kernel(
    const int* __restrict__ types, const float* __restrict__ emb,
    const float* __restrict__ W, const float* __restrict__ b,
    const float* __restrict__ g, const float* __restrict__ beta,
    unsigned short* __restrict__ x,
    const float* __restrict__ Wl, const float* __restrict__ Wr,
    unsigned short* __restrict__ wt,
    const int* __restrict__ dsts, int* __restrict__ deg, int e,
    int n, int nbEmbed) {
    __shared__ float sW[NID * D];
    __shared__ float semb[3 * NID];
    int blk = blockIdx.x;
    int t = threadIdx.x;
    if (blk < nbEmbed) {
        for (int i = t; i < NID * D; i += 256) sW[i] = W[i];
        for (int i = t; i < 3 * NID; i += 256) semb[i] = emb[i];
        __syncthreads();
        int lane = t & 63, w = t >> 6;
        int node = blk * 4 + w;
        if (node >= n) return;
        int c0 = 2 * lane;
        int ty = types[node];
        const float* ev = &semb[ty * NID];
        float v0 = b[c0], v1 = b[c0 + 1];
        #pragma unroll
        for (int k = 0; k < NID; ++k) {
            float ek = ev[k];
            v0 = fmaf(ek, sW[k * D + c0], v0);
            v1 = fmaf(ek, sW[k * D + c0 + 1], v1);
        }
        float s = v0 + v1, sq = v0 * v0 + v1 * v1;
        #pragma unroll
        for (int off = 1; off < 64; off <<= 1) {
            s  += __shfl_xor(s, off, 64);
            sq += __shfl_xor(sq, off, 64);
        }
        float mu  = s * (1.0f / D);
        float var = sq * (1.0f / D) - mu * mu;
        float r   = rsqrtf(var + EPS);
        v0 = fmaxf((v0 - mu) * r * g[c0]     + beta[c0],     0.0f);
        v1 = fmaxf((v1 - mu) * r * g[c0 + 1] + beta[c0 + 1], 0.0f);
        unsigned int packed = (unsigned int)f2bf(v0) | ((unsigned int)f2bf(v1) << 16);
        *(unsigned int*)(x + (size_t)node * D + c0) = packed;
    } else if (blk < nbEmbed + 512) {
        int idx = (blk - nbEmbed) * 256 + t;   // L*2*D*D = 131072
        int k    = idx & (D - 1);
        int nrow = (idx >> 7) & (D - 1);
        int s    = (idx >> 14) & 1;
        int l    = idx >> 15;
        const float* Wm = s ? Wr : Wl;
        wt[idx] = f2bf(Wm[(size_t)l * D * D + (size_t)k * D + nrow]);
    } else {
        int i = (blk - nbEmbed - 512) * 256 + t;
        if (i < e) atomicAdd(&deg[dsts[i]], 1);   // count_deg (deg pre-zeroed)
    }
}

// ---------------------------------------------------------------------------
// Dual GEMM via bf16 MFMA; bf16 in. xl out as FP8 e4m3 (halves the agg
// gather traffic -- agg showed ~77MB HBM FETCH/dispatch, memory-floor
// bound); xr out fp16 (read once per node, negligible). Layer 0: extra
// blocks past ntiles run the CSR scatter.
// ---------------------------------------------------------------------------
__global__ __launch_bounds__(256) void dual_gemm_mfma_kernel(
    const unsigned short* __restrict__ x, const unsigned short* __restrict__ wt,
    const float* __restrict__ bl, const float* __restrict__ br,
    unsigned char* __restrict__ xl, unsigned short* __restrict__ xr, int n,
    int ntiles,
    const int* __restrict__ srcs, const int* __restrict__ dsts, int e,
    int* __restrict__ cursor, int* __restrict__ csr_src) {
    __shared__ __align__(16) unsigned short sa[64 * 136];
    int t = threadIdx.x;
    if (blockIdx.x >= ntiles) {
        // ---- scatter blocks (layer 0 only): dst-sorted CSR, self loops ----
        int i = (blockIdx.x - ntiles) * 256 + t;
        if (i < e) {
            int pos = atomicAdd(&cursor[dsts[i]], 1);
            csr_src[pos] = srcs[i];
        } else if (i < e + n) {
            int node = i - e;
            int pos = atomicAdd(&cursor[node], 1);
            csr_src[pos] = node;  // self loop
        }
        return;
    }
    int nbase = blockIdx.x * 64;
    int rows = n - nbase; if (rows > 64) rows = 64;
    int lane = t & 63, w = t >> 6;
    int L = lane & 15, q = lane >> 4;
    int s  = w >> 1;          // 0: Wl, 1: Wr
    int n0 = (w & 1) * 64;    // col strip base within this matrix
    const unsigned short* wb = wt + ((size_t)s * D + n0) * D;
    // ---- preload all B fragments ----
    short8 b[4][4];           // [kk][ni]
    #pragma unroll
    for (int kk = 0; kk < 4; ++kk)
        #pragma unroll
        for (int ni = 0; ni < 4; ++ni)
            b[kk][ni] = *(const short8*)(wb + (size_t)(ni * 16 + L) * D + kk * 32 + q * 8);
    // ---- stage bf16 x -> LDS (stride 136) ----
    {
        int r   = t >> 2;
        int seg = t & 3;                 // 32 ch = 64 B each
        uint4* drow = (uint4*)(sa + r * 136 + seg * 32);
        if (r < rows) {
            const uint4* srow = (const uint4*)(x + (size_t)(nbase + r) * D + seg * 32);
            drow[0] = srow[0]; drow[1] = srow[1]; drow[2] = srow[2]; drow[3] = srow[3];
        } else {
            uint4 z = make_uint4(0, 0, 0, 0);
            drow[0] = z; drow[1] = z; drow[2] = z; drow[3] = z;
        }
    }
    __syncthreads();
    floatx4 acc[4][4];
    #pragma unroll
    for (int mi = 0; mi < 4; ++mi)
        #pragma unroll
        for (int ni = 0; ni < 4; ++ni)
            acc[mi][ni] = (floatx4){0.0f, 0.0f, 0.0f, 0.0f};
    #pragma unroll
    for (int kk = 0; kk < 4; ++kk) {
        int ko = kk * 32 + q * 8;
        short8 a[4];
        #pragma unroll
        for (int mi = 0; mi < 4; ++mi)
            a[mi] = *(const short8*)(sa + (mi * 16 + L) * 136 + ko);
        #pragma unroll
        for (int mi = 0; mi < 4; ++mi)
            #pragma unroll
            for (int ni = 0; ni < 4; ++ni)
                acc[mi][ni] = __builtin_amdgcn_mfma_f32_16x16x32_bf16(a[mi], b[kk][ni], acc[mi][ni], 0, 0, 0);
    }
    const float* bias = s ? br : bl;
    // ---- pass 0: xl as fp8 e4m3 (128 B/row) ----
    __syncthreads();
    if (s == 0) {
        unsigned char* sb = (unsigned char*)sa;
        #pragma unroll
        for (int ni = 0; ni < 4; ++ni) {
            int col = n0 + ni * 16 + L;
            float bv = bias[col];
            #pragma unroll
            for (int mi = 0; mi < 4; ++mi) {
                #pragma unroll
                for (int r = 0; r < 4; ++r) {
                    int row = mi * 16 + q * 4 + r;
                    sb[row * 272 + col] = f2fp8(acc[mi][ni][r] + bv);
                }
            }
        }
    }
    __syncthreads();
    {
        unsigned char* sb = (unsigned char*)sa;
        #pragma unroll
        for (int c = 0; c < 2; ++c) {
            int chunk = c * 256 + t;        // 0..511
            int row   = chunk >> 3;
            int off   = (chunk & 7) * 16;
            if (row < rows) {
                uint4 v = *(const uint4*)(sb + row * 272 + off);
                *(uint4*)(xl + (size_t)(nbase + row) * D + off) = v;
            }
        }
    }
    // ---- pass 1: xr as fp16 (256 B/row) ----
    __syncthreads();
    if (s == 1) {
        #pragma unroll
        for (int ni = 0; ni < 4; ++ni) {
            int col = n0 + ni * 16 + L;
            float bv = bias[col];
            #pragma unroll
            for (int mi = 0; mi < 4; ++mi) {
                #pragma unroll
                for (int r = 0; r < 4; ++r) {
                    int row = mi * 16 + q * 4 + r;
                    sa[row * 136 + col] = f2h(acc[mi][ni][r] + bv);
                }
            }
        }
    }
    __syncthreads();
    #pragma unroll
    for (int c = 0; c < 4; ++c) {
        int chunk = c * 256 + t;        // 0..1023
        int row   = chunk >> 4;
        int off   = (chunk & 15) * 8;
        if (row < rows) {
            short8 v = *(const short8*)(sa + row * 136 + off);
            *(short8*)(xr + (size_t)(nbase + row) * D + off) = v;
        }
    }
}

// ---------------------------------------------------------------------------
// Fused GATv2 aggregation. xl gathered as FP8 e4m3 (8 B/lane vs 16) --
// halves the ~77MB/dispatch HBM gather traffic. Decode: 2x cvt_pk_f32_fp8
// + 2x cvt_pkrtz per dword (8 insts/trip). MLP + pk_fma acc in fp16
// unchanged. att pre-scaled by log2(e) -> bare exp2f.
// NOTE (r8/r9): persistent-kernel fusion NOT viable -- software grid
// barriers cost ~90-145us each at 720 blocks on gfx950.
// ---------------------------------------------------------------------------
__global__ __launch_bounds__(256) void gat_agg_kernel(
    const unsigned char* __restrict__ xl, const unsigned short* __restrict__ xr,
    const unsigned short* __restrict__ xin,
    const int* __restrict__ offs, const int* __restrict__ csr_src,
    const float* __restrict__ att,
    const float* __restrict__ gbias,
    const float* __restrict__ lng, const float* __restrict__ lnb,
    unsigned short* __restrict__ xout_bf, float* __restrict__ xout_f32, int n) {
    int t = threadIdx.x;
    int lane = t & 63, w = t >> 6;
    int node = blockIdx.x * 4 + w;
    if (node >= n) return;
    int g  = lane >> 4;       // edge slot 0..3
    int l  = lane & 15;       // channel block 0..15 (8 ch each)
    int cb = l * 8;
    h2 xr2[4], at2[4];
    {
        uint4 u = *(const uint4*)(xr + (size_t)node * D + cb);
        xr2[0] = u2h2(u.x); xr2[1] = u2h2(u.y); xr2[2] = u2h2(u.z); xr2[3] = u2h2(u.w);
        float4 t0 = *(const float4*)(att + cb);
        float4 t1 = *(const float4*)(att + cb + 4);
        at2[0] = (h2){(_Float16)(t0.x * LOG2E), (_Float16)(t0.y * LOG2E)};
        at2[1] = (h2){(_Float16)(t0.z * LOG2E), (_Float16)(t0.w * LOG2E)};
        at2[2] = (h2){(_Float16)(t1.x * LOG2E), (_Float16)(t1.y * LOG2E)};
        at2[3] = (h2){(_Float16)(t1.z * LOG2E), (_Float16)(t1.w * LOG2E)};
    }
    h2 acch[4];
    #pragma unroll
    for (int i = 0; i < 4; ++i) acch[i] = (h2){(_Float16)0.0f, (_Float16)0.0f};
    float lsum = 0.0f;
    int s0 = offs[node], s1 = offs[node + 1];
    // ---- 2-deep pipeline prologue (fp8 rows: uint2 = 8 ch/lane) ----
    int j0 = s0 + g;
    bool val_c = j0 < s1;
    int src_c = csr_src[val_c ? j0 : s0];
    uint2 u_c = *(const uint2*)(xl + (size_t)src_c * D + cb);
    int j1 = j0 + 4;
    bool val_n = j1 < s1;
    int src_n = csr_src[val_n ? j1 : s0];
    uint2 u_n = *(const uint2*)(xl + (size_t)src_n * D + cb);
    int j2 = j0 + 8;
    bool val_2 = j2 < s1;
    int src_2 = csr_src[val_2 ? j2 : s0];
    for (int j = s0; j < s1; j += 4) {
        // issue gather(i+2)
        uint2 u_2 = *(const uint2*)(xl + (size_t)src_2 * D + cb);
        // issue idx(i+3)
        int j3 = j + 12 + g;
        bool val_3 = j3 < s1;
        int src_3 = csr_src[val_3 ? j3 : s0];
        // consume gather(i): fp8 -> h2, packed f16 edge MLP
        h2 xv2[4];
        fp8x4_to_h2x2(u_c.x, xv2);
        fp8x4_to_h2x2(u_c.y, xv2 + 2);
        float p = 0.0f;
        #pragma unroll
        for (int i = 0; i < 4; ++i) {
            h2 e  = xv2[i] + xr2[i];
            h2 el = __builtin_elementwise_max(e, e * (_Float16)NEG);  // leaky_relu
            p = __builtin_amdgcn_fdot2(el, at2[i], p, false);
        }
        p += __shfl_xor(p, 1, 64);      // reduce over the head's 4 lanes
        p += __shfl_xor(p, 2, 64);
        float wgt = val_c ? exp2f(p) : 0.0f;   // att pre-scaled by log2e
        lsum += wgt;
        _Float16 wh = (_Float16)wgt;
        h2 w2 = {wh, wh};
        #pragma unroll
        for (int i = 0; i < 4; ++i) acch[i] += w2 * xv2[i];   // v_pk_fma_f16
        // shift pipeline
        u_c = u_n; u_n = u_2;
        val_c = val_n; val_n = val_2;
        val_2 = val_3; src_2 = src_3;
    }
    // widen to f32, then cross-group reduction (sum over the 4 edge slots)
    float acc[8];
    #pragma unroll
    for (int i = 0; i < 4; ++i) {
        acc[2 * i]     = (float)acch[i][0];
        acc[2 * i + 1] = (float)acch[i][1];
    }
    #pragma unroll
    for (int i = 0; i < 8; ++i) {
        acc[i] += __shfl_xor(acc[i], 16, 64);
        acc[i] += __shfl_xor(acc[i], 32, 64);
    }
    lsum += __shfl_xor(lsum, 16, 64);
    lsum += __shfl_xor(lsum, 32, 64);
    float inv = 1.0f / lsum;
    // bias + residual (bf16)
    float xi[8];
    {
        uint4 u = *(const uint4*)(xin + (size_t)node * D + cb);
        float2 a = bf2_to_f2(u.x), b = bf2_to_f2(u.y), c = bf2_to_f2(u.z), d = bf2_to_f2(u.w);
        xi[0]=a.x; xi[1]=a.y; xi[2]=b.x; xi[3]=b.y; xi[4]=c.x; xi[5]=c.y; xi[6]=d.x; xi[7]=d.y;
    }
    float4 gb0 = *(const float4*)(gbias + cb);
    float4 gb1 = *(const float4*)(gbias + cb + 4);
    float gb[8] = {gb0.x, gb0.y, gb0.z, gb0.w, gb1.x, gb1.y, gb1.z, gb1.w};
    float v[8];
    #pragma unroll
    for (int i = 0; i < 8; ++i) v[i] = fmaf(acc[i], inv, gb[i] + xi[i]);
    // LayerNorm over the 16 channel-block lanes
    float s = 0.0f, sq = 0.0f;
    #pragma unroll
    for (int i = 0; i < 8; ++i) { s += v[i]; sq = fmaf(v[i], v[i], sq); }
    #pragma unroll
    for (int off = 1; off < 16; off <<= 1) {
        s  += __shfl_xor(s, off, 64);
        sq += __shfl_xor(sq, off, 64);
    }
    float mu  = s * (1.0f / D);
    float var = sq * (1.0f / D) - mu * mu;
    float r   = rsqrtf(var + EPS);
    float4 lg0 = *(const float4*)(lng + cb);
    float4 lg1 = *(const float4*)(lng + cb + 4);
    float4 lb0 = *(const float4*)(lnb + cb);
    float4 lb1 = *(const float4*)(lnb + cb + 4);
    float lg[8] = {lg0.x, lg0.y, lg0.z, lg0.w, lg1.x, lg1.y, lg1.z, lg1.w};
    float lb[8] = {lb0.x, lb0.y, lb0.z, lb0.w, lb1.x, lb1.y, lb1.z, lb1.w};
    float o[8];
    #pragma unroll
    for (int i = 0; i < 8; ++i) o[i] = fmaxf((v[i] - mu) * r * lg[i] + lb[i], 0.0f);
    if (g == 0) {
        if (xout_f32) {
            *(float4*)(xout_f32 + (size_t)node * D + cb)     = make_float4(o[0], o[1], o[2], o[3]);
            *(float4*)(xout_f32 + (size_t)node * D + cb + 4) = make_float4(o[4], o[5], o[6], o[7]);
        } else {
            unsigned int p0 = (unsigned int)f2bf(o[0]) | ((unsigned int)f2bf(o[1]) << 16);
            unsigned int p1 = (unsigned int)f2bf(o[2]) | ((unsigned int)f2bf(o[3]) << 16);
            unsigned int p2 = (unsigned int)f2bf(o[4]) | ((unsigned int)f2bf(o[5]) << 16);
            unsigned int p3 = (unsigned int)f2bf(o[6]) | ((unsigned int)f2bf(o[7]) << 16);
            *(uint4*)(xout_bf + (size_t)node * D + cb) = make_uint4(p0, p1, p2, p3);
        }
    }
}

// ---------------------------------------------------------------------------
extern "C" void kernel_launch(void* const* d_in, const int* in_sizes, int n_in,
                              void* d_out, int out_size, void* d_ws, size_t ws_size,
                              hipStream_t stream) {
    const int*   node_types = (const int*)d_in[0];
    const int*   edge_index = (const int*)d_in[1];
    const float* emb        = (const float*)d_in[2];
    const float* projW      = (const float*)d_in[3];
    const float* projb      = (const float*)d_in[4];
    const float* projg      = (const float*)d_in[5];
    const float* projbeta   = (const float*)d_in[6];
    const float* Wl         = (const float*)d_in[7];
    const float* bl         = (const float*)d_in[8];
    const float* Wr         = (const float*)d_in[9];
    const float* br         = (const float*)d_in[10];
    const float* att        = (const float*)d_in[11];
    const float* gbias      = (const float*)d_in[12];
    const float* lng        = (const float*)d_in[13];
    const float* lnb        = (const float*)d_in[14];
    float* out = (float*)d_out;

    int n = in_sizes[0];
    int e = in_sizes[1] / 2;
    const int* srcs = edge_index;
    const int* dsts = edge_index + e;

    char* p = (char*)d_ws;
    auto carve = [&](size_t bytes) {
        char* q = p;
        p += (bytes + 255) & ~(size_t)255;
        return q;
    };
    int*   deg     = (int*)carve((size_t)n * 4);
    int*   offs    = (int*)carve((size_t)(n + 1) * 4);
    int*   cursor  = (int*)carve((size_t)n * 4);
    int*   bsum    = (int*)carve(256 * 4);
    int*   csr_src = (int*)carve((size_t)(e + n) * 4);
    unsigned short* xbuf = (unsigned short*)carve((size_t)n * D * 2);
    unsigned char*  xlb  = (unsigned char*)carve((size_t)n * D);       // fp8
    unsigned short* xrb  = (unsigned short*)carve((size_t)n * D * 2);  // fp16
    unsigned short* wt   = (unsigned short*)carve((size_t)NLAYER * 2 * D * D * 2);

    int nb = (n + 255) / 256;        // 196 for N=50000
    int nbEmbed = (n + 3) / 4;       // 12500
    int nbE = (e + 255) / 256;       // count blocks
    int ntiles = (n + 63) / 64;      // GEMM tiles
    int nscat  = (e + n + 255) / 256;// scatter blocks

    // ---- deg := 0 (count_deg runs inside setup; self loop folded into scan)
    hipMemsetAsync(deg, 0, (size_t)n * 4, stream);

    // ---- fused setup: embed/proj/LN -> bf16 x ; W -> bf16 W^T ; count_deg ----
    setup_kernel<<<nbEmbed + 512 + nbE, 256, 0, stream>>>(
        node_types, emb, projW, projb, projg, projbeta, xbuf,
        Wl, Wr, wt, dsts, deg, e, n, nbEmbed);

    // ---- CSR offsets ----
    scan_blocks_kernel<<<nb, 256, 0, stream>>>(deg, offs, bsum, n);
    scan_add_kernel<<<nb, 256, 0, stream>>>(offs, bsum, cursor, n, nb, e + n);

    // ---- 4 GATv2 layers; layer-0 GEMM dispatch also runs the CSR scatter ----
    for (int layer = 0; layer < NLAYER; ++layer) {
        int extra = (layer == 0) ? nscat : 0;
        dual_gemm_mfma_kernel<<<ntiles + extra, 256, 0, stream>>>(
            xbuf, wt + (size_t)layer * 2 * D * D,
            bl + (size_t)layer * D, br + (size_t)layer * D, xlb, xrb, n,
            ntiles, srcs, dsts, e, cursor, csr_src);
        bool last = (layer == NLAYER - 1);
        gat_agg_kernel<<<(n + 3) / 4, 256, 0, stream>>>(
            xlb, xrb, xbuf, offs, csr_src,
            att + (size_t)layer * H * CH, gbias + (size_t)layer * D,
            lng + (size_t)layer * D, lnb + (size_t)layer * D,
            last ? (unsigned short*)nullptr : xbuf, last ? out : (float*)nullptr, n);
    }
}

// Round 14
// 353.150 us; speedup vs baseline: 1.1327x; 1.1149x over previous
//
#include <hip/hip_runtime.h>
#include <hip/hip_bf16.h>
#include <math.h>

#define D      128
#define NID    16
#define H      4
#define CH     32
#define NLAYER 4
#define EPS    1e-5f
#define NEG    0.2f
#define LOG2E  1.442695040888963f
#define SRCMASK 0x0FFFFFFF

typedef __attribute__((ext_vector_type(8))) short short8;
typedef __attribute__((ext_vector_type(4))) float floatx4;
typedef _Float16 h2 __attribute__((ext_vector_type(2)));
typedef float fx2 __attribute__((ext_vector_type(2)));

__device__ __forceinline__ float2 bf2_to_f2(unsigned int u) {
    float2 r;
    unsigned int lo = u << 16;
    unsigned int hi = u & 0xffff0000u;
    r.x = __uint_as_float(lo);
    r.y = __uint_as_float(hi);
    return r;
}

__device__ __forceinline__ unsigned short f2bf(float f) {
    __hip_bfloat16 h = __float2bfloat16(f);
    return *reinterpret_cast<unsigned short*>(&h);
}

__device__ __forceinline__ unsigned short f2h(float f) {
    _Float16 h = (_Float16)f;
    unsigned short u;
    __builtin_memcpy(&u, &h, 2);
    return u;
}

__device__ __forceinline__ h2 u2h2(unsigned int u) {
    h2 v;
    __builtin_memcpy(&v, &u, 4);
    return v;
}

__device__ __forceinline__ h2 pkrtz(float a, float b) {
    auto r = __builtin_amdgcn_cvt_pkrtz(a, b);
    h2 out;
    __builtin_memcpy(&out, &r, 4);
    return out;
}

// fp8 e4m3 (OCP on gfx950) encode of one float -> byte
__device__ __forceinline__ unsigned char f2fp8(float v) {
    int pk = __builtin_amdgcn_cvt_pk_fp8_f32(v, v, 0, false);
    return (unsigned char)(pk & 0xff);
}

// decode 4 fp8 bytes (one dword) -> 2x h2
__device__ __forceinline__ void fp8x4_to_h2x2(unsigned int w, h2* out) {
    fx2 f0 = __builtin_amdgcn_cvt_pk_f32_fp8((int)w, false);
    fx2 f1 = __builtin_amdgcn_cvt_pk_f32_fp8((int)w, true);
    out[0] = pkrtz(f0[0], f0[1]);
    out[1] = pkrtz(f1[0], f1[1]);
}

// ---------------------------------------------------------------------------
// KEY STRUCTURE (round 13): only 3 node types exist, so x = proj(emb[type])
// has 3 distinct rows, and so do layer-0's xl/xr. proj3 computes those 3 rows
// once; the per-node projection, xbuf materialization and layer-0 GEMM are
// all DELETED. Scatter packs type[src] into csr_src bits 28-29; layer-0 agg
// gathers from the 384B L1-resident xl3 table.
// r12 profile: setup_kernel was 47.7us (latency-bound on 12500 tiny blocks).
// ---------------------------------------------------------------------------

__global__ __launch_bounds__(256) void scan_blocks_kernel(const int* __restrict__ deg, int* __restrict__ offs,
                                                          int* __restrict__ bsum, int n) {
    __shared__ int sw[8];
    int t = threadIdx.x;
    int i = blockIdx.x * 256 + t;
    int v = (i < n) ? deg[i] + 1 : 0;   // +1 = self loop
    int lane = t & 63, w = t >> 6;
    int x = v;
    #pragma unroll
    for (int off = 1; off < 64; off <<= 1) {
        int y = __shfl_up(x, off, 64);
        if (lane >= off) x += y;
    }
    if (lane == 63) sw[w] = x;
    __syncthreads();
    if (t == 0) {
        int s = 0;
        for (int k = 0; k < 4; ++k) { int tv = sw[k]; sw[k] = s; s += tv; }
        sw[4] = s;
    }
    __syncthreads();
    int excl = x - v + sw[w];
    if (i < n) offs[i] = excl;
    if (t == 255) bsum[blockIdx.x] = sw[4];
}

__global__ __launch_bounds__(256) void scan_add_kernel(int* __restrict__ offs, const int* __restrict__ bsum,
                                                       int* __restrict__ cursor, int n, int nb, int total) {
    __shared__ int sw[8];
    __shared__ int sS;
    int t = threadIdx.x;
    int bid = blockIdx.x;
    int v = (t < bid && t < nb) ? bsum[t] : 0;
    int lane = t & 63, w = t >> 6;
    #pragma unroll
    for (int off = 32; off > 0; off >>= 1) v += __shfl_xor(v, off, 64);
    if (lane == 0) sw[w] = v;
    __syncthreads();
    if (t == 0) sS = sw[0] + sw[1] + sw[2] + sw[3];
    __syncthreads();
    int S = sS;
    int i = bid * 256 + t;
    if (i < n) {
        int o = offs[i] + S;
        offs[i] = o;
        cursor[i] = o;
    }
    if (i == 0) offs[n] = total;
}

// scatter: dst-sorted CSR with type packed in bits 28-29 (src < 2^26)
__global__ __launch_bounds__(256) void scatter_kernel(
    const int* __restrict__ srcs, const int* __restrict__ dsts,
    const int* __restrict__ types,
    int e, int n, int* cursor, int* __restrict__ csr_src) {
    int i = blockIdx.x * blockDim.x + threadIdx.x;
    if (i < e) {
        int s = srcs[i];
        int ty = types[s];               // 200KB table, L2-resident
        int pos = atomicAdd(&cursor[dsts[i]], 1);
        csr_src[pos] = s | (ty << 28);
    } else if (i < e + n) {
        int node = i - e;
        int ty = types[node];
        int pos = atomicAdd(&cursor[node], 1);
        csr_src[pos] = node | (ty << 28);  // self loop
    }
}

// ---------------------------------------------------------------------------
// Setup: [0,512) W->bf16 W^T for layers 1-3 (and 0, unused); [512,512+nbE)
// count_deg; [last block] proj3: the 3 distinct rows of x, xl0, xr0.
// ---------------------------------------------------------------------------
__global__ __launch_bounds__(256) void setup_kernel(
    const float* __restrict__ emb,
    const float* __restrict__ W, const float* __restrict__ pb,
    const float* __restrict__ pg, const float* __restrict__ pbeta,
    const float* __restrict__ Wl, const float* __restrict__ Wr,
    const float* __restrict__ bl, const float* __restrict__ br,
    unsigned short* __restrict__ wt,
    const int* __restrict__ dsts, int* __restrict__ deg, int e,
    unsigned short* __restrict__ x3bf, unsigned char* __restrict__ xl3,
    unsigned short* __restrict__ xr3,
    int nbE) {
    __shared__ float sbuf[NID * D];      // aliased: p3 | x3s | red
    __shared__ float semb[3 * NID];
    int blk = blockIdx.x;
    int t = threadIdx.x;
    if (blk < 512) {
        int idx = blk * 256 + t;         // L*2*D*D = 131072
        int k    = idx & (D - 1);
        int nrow = (idx >> 7) & (D - 1);
        int s    = (idx >> 14) & 1;
        int l    = idx >> 15;
        const float* Wm = s ? Wr : Wl;
        wt[idx] = f2bf(Wm[(size_t)l * D * D + (size_t)k * D + nrow]);
    } else if (blk < 512 + nbE) {
        int i = (blk - 512) * 256 + t;
        if (i < e) atomicAdd(&deg[dsts[i]], 1);   // count_deg (deg pre-zeroed)
    } else {
        // ---- proj3: 3 rows of x (bf16), xl0 (fp8), xr0 (fp16) ----
        float* p3  = sbuf;               // [3][128]
        float* x3s = sbuf + 384;         // [3][128] bf16-rounded f32
        float* red = sbuf + 768;         // [4]
        for (int i = t; i < 3 * NID; i += 256) semb[i] = emb[i];
        __syncthreads();
        int c = t;
        if (c < D) {
            float wcol[NID];
            #pragma unroll
            for (int k = 0; k < NID; ++k) wcol[k] = W[k * D + c];
            float bc = pb[c];
            #pragma unroll
            for (int ty = 0; ty < 3; ++ty) {
                float a = bc;
                #pragma unroll
                for (int k = 0; k < NID; ++k) a = fmaf(semb[ty * NID + k], wcol[k], a);
                p3[ty * D + c] = a;
            }
        }
        __syncthreads();
        #pragma unroll 1
        for (int ty = 0; ty < 3; ++ty) {
            float v = (c < D) ? p3[ty * D + c] : 0.0f;
            float s = v, sq = v * v;
            #pragma unroll
            for (int off = 1; off < 64; off <<= 1) {
                s  += __shfl_xor(s, off, 64);
                sq += __shfl_xor(sq, off, 64);
            }
            if ((t & 63) == 0 && t < 128) { red[(t >> 6) * 2] = s; red[(t >> 6) * 2 + 1] = sq; }
            __syncthreads();
            float S = red[0] + red[2], SQ = red[1] + red[3];
            float mu = S * (1.0f / D), var = SQ * (1.0f / D) - mu * mu;
            float r = rsqrtf(var + EPS);
            if (c < D) {
                float o = fmaxf((p3[ty * D + c] - mu) * r * pg[c] + pbeta[c], 0.0f);
                unsigned short bfv = f2bf(o);
                x3s[ty * D + c] = __uint_as_float((unsigned int)bfv << 16);
                x3bf[ty * D + c] = bfv;
            }
            __syncthreads();
        }
        // xl3 / xr3 (layer 0 weights, f32 direct)
        if (c < D) {
            #pragma unroll 1
            for (int ty = 0; ty < 3; ++ty) {
                float al = bl[c], ar = br[c];
                for (int k = 0; k < D; ++k) {
                    float xv = x3s[ty * D + k];
                    al = fmaf(xv, Wl[(size_t)k * D + c], al);
                    ar = fmaf(xv, Wr[(size_t)k * D + c], ar);
                }
                xl3[ty * D + c] = f2fp8(al);
                xr3[ty * D + c] = f2h(ar);
            }
        }
    }
}

// ---------------------------------------------------------------------------
// Dual GEMM via bf16 MFMA (layers 1-3 only); bf16 in, fp8 xl / fp16 xr out.
// ---------------------------------------------------------------------------
__global__ __launch_bounds__(256) void dual_gemm_mfma_kernel(
    const unsigned short* __restrict__ x, const unsigned short* __restrict__ wt,
    const float* __restrict__ bl, const float* __restrict__ br,
    unsigned char* __restrict__ xl, unsigned short* __restrict__ xr, int n) {
    __shared__ __align__(16) unsigned short sa[64 * 136];
    int t = threadIdx.x;
    int nbase = blockIdx.x * 64;
    int rows = n - nbase; if (rows > 64) rows = 64;
    int lane = t & 63, w = t >> 6;
    int L = lane & 15, q = lane >> 4;
    int s  = w >> 1;
    int n0 = (w & 1) * 64;
    const unsigned short* wb = wt + ((size_t)s * D + n0) * D;
    short8 b[4][4];
    #pragma unroll
    for (int kk = 0; kk < 4; ++kk)
        #pragma unroll
        for (int ni = 0; ni < 4; ++ni)
            b[kk][ni] = *(const short8*)(wb + (size_t)(ni * 16 + L) * D + kk * 32 + q * 8);
    {
        int r   = t >> 2;
        int seg = t & 3;
        uint4* drow = (uint4*)(sa + r * 136 + seg * 32);
        if (r < rows) {
            const uint4* srow = (const uint4*)(x + (size_t)(nbase + r) * D + seg * 32);
            drow[0] = srow[0]; drow[1] = srow[1]; drow[2] = srow[2]; drow[3] = srow[3];
        } else {
            uint4 z = make_uint4(0, 0, 0, 0);
            drow[0] = z; drow[1] = z; drow[2] = z; drow[3] = z;
        }
    }
    __syncthreads();
    floatx4 acc[4][4];
    #pragma unroll
    for (int mi = 0; mi < 4; ++mi)
        #pragma unroll
        for (int ni = 0; ni < 4; ++ni)
            acc[mi][ni] = (floatx4){0.0f, 0.0f, 0.0f, 0.0f};
    #pragma unroll
    for (int kk = 0; kk < 4; ++kk) {
        int ko = kk * 32 + q * 8;
        short8 a[4];
        #pragma unroll
        for (int mi = 0; mi < 4; ++mi)
            a[mi] = *(const short8*)(sa + (mi * 16 + L) * 136 + ko);
        #pragma unroll
        for (int mi = 0; mi < 4; ++mi)
            #pragma unroll
            for (int ni = 0; ni < 4; ++ni)
                acc[mi][ni] = __builtin_amdgcn_mfma_f32_16x16x32_bf16(a[mi], b[kk][ni], acc[mi][ni], 0, 0, 0);
    }
    const float* bias = s ? br : bl;
    // pass 0: xl fp8
    __syncthreads();
    if (s == 0) {
        unsigned char* sb = (unsigned char*)sa;
        #pragma unroll
        for (int ni = 0; ni < 4; ++ni) {
            int col = n0 + ni * 16 + L;
            float bv = bias[col];
            #pragma unroll
            for (int mi = 0; mi < 4; ++mi) {
                #pragma unroll
                for (int r = 0; r < 4; ++r) {
                    int row = mi * 16 + q * 4 + r;
                    sb[row * 272 + col] = f2fp8(acc[mi][ni][r] + bv);
                }
            }
        }
    }
    __syncthreads();
    {
        unsigned char* sb = (unsigned char*)sa;
        #pragma unroll
        for (int c = 0; c < 2; ++c) {
            int chunk = c * 256 + t;
            int row   = chunk >> 3;
            int off   = (chunk & 7) * 16;
            if (row < rows) {
                uint4 v = *(const uint4*)(sb + row * 272 + off);
                *(uint4*)(xl + (size_t)(nbase + row) * D + off) = v;
            }
        }
    }
    // pass 1: xr fp16
    __syncthreads();
    if (s == 1) {
        #pragma unroll
        for (int ni = 0; ni < 4; ++ni) {
            int col = n0 + ni * 16 + L;
            float bv = bias[col];
            #pragma unroll
            for (int mi = 0; mi < 4; ++mi) {
                #pragma unroll
                for (int r = 0; r < 4; ++r) {
                    int row = mi * 16 + q * 4 + r;
                    sa[row * 136 + col] = f2h(acc[mi][ni][r] + bv);
                }
            }
        }
    }
    __syncthreads();
    #pragma unroll
    for (int c = 0; c < 4; ++c) {
        int chunk = c * 256 + t;
        int row   = chunk >> 4;
        int off   = (chunk & 15) * 8;
        if (row < rows) {
            short8 v = *(const short8*)(sa + row * 136 + off);
            *(short8*)(xr + (size_t)(nbase + row) * D + off) = v;
        }
    }
}

// ---------------------------------------------------------------------------
// Fused GATv2 aggregation. L0: gathers from the 384B L1-resident xl3 table
// via type bits (csr_src[31:28]); xr/residual from xr3/x3bf via types[node].
// L1-3: fp8 xl gather (src = csr_src & SRCMASK). fp16 packed MLP + pk_fma.
// ---------------------------------------------------------------------------
template<bool L0>
__global__ __launch_bounds__(256) void gat_agg_kernel(
    const unsigned char* __restrict__ xl, const unsigned short* __restrict__ xr,
    const unsigned short* __restrict__ xin,
    const unsigned char* __restrict__ xl3, const unsigned short* __restrict__ xr3,
    const unsigned short* __restrict__ x3bf, const int* __restrict__ types,
    const int* __restrict__ offs, const int* __restrict__ csr_src,
    const float* __restrict__ att,
    const float* __restrict__ gbias,
    const float* __restrict__ lng, const float* __restrict__ lnb,
    unsigned short* __restrict__ xout_bf, float* __restrict__ xout_f32, int n) {
    int t = threadIdx.x;
    int lane = t & 63, w = t >> 6;
    int node = blockIdx.x * 4 + w;
    if (node >= n) return;
    int g  = lane >> 4;
    int l  = lane & 15;
    int cb = l * 8;
    int tyn = L0 ? types[node] : 0;
    const unsigned short* xrrow = L0 ? (xr3 + (size_t)tyn * D) : (xr + (size_t)node * D);
    h2 xr2[4], at2[4];
    {
        uint4 u = *(const uint4*)(xrrow + cb);
        xr2[0] = u2h2(u.x); xr2[1] = u2h2(u.y); xr2[2] = u2h2(u.z); xr2[3] = u2h2(u.w);
        float4 t0 = *(const float4*)(att + cb);
        float4 t1 = *(const float4*)(att + cb + 4);
        at2[0] = (h2){(_Float16)(t0.x * LOG2E), (_Float16)(t0.y * LOG2E)};
        at2[1] = (h2){(_Float16)(t0.z * LOG2E), (_Float16)(t0.w * LOG2E)};
        at2[2] = (h2){(_Float16)(t1.x * LOG2E), (_Float16)(t1.y * LOG2E)};
        at2[3] = (h2){(_Float16)(t1.z * LOG2E), (_Float16)(t1.w * LOG2E)};
    }
    auto rowp = [&](int v) -> const unsigned char* {
        if (L0) return xl3 + (size_t)((v >> 28) & 3) * D;
        return xl + (size_t)(v & SRCMASK) * D;
    };
    h2 acch[4];
    #pragma unroll
    for (int i = 0; i < 4; ++i) acch[i] = (h2){(_Float16)0.0f, (_Float16)0.0f};
    float lsum = 0.0f;
    int s0 = offs[node], s1 = offs[node + 1];
    int j0 = s0 + g;
    bool val_c = j0 < s1;
    int src_c = csr_src[val_c ? j0 : s0];
    uint2 u_c = *(const uint2*)(rowp(src_c) + cb);
    int j1 = j0 + 4;
    bool val_n = j1 < s1;
    int src_n = csr_src[val_n ? j1 : s0];
    uint2 u_n = *(const uint2*)(rowp(src_n) + cb);
    int j2 = j0 + 8;
    bool val_2 = j2 < s1;
    int src_2 = csr_src[val_2 ? j2 : s0];
    for (int j = s0; j < s1; j += 4) {
        uint2 u_2 = *(const uint2*)(rowp(src_2) + cb);
        int j3 = j + 12 + g;
        bool val_3 = j3 < s1;
        int src_3 = csr_src[val_3 ? j3 : s0];
        h2 xv2[4];
        fp8x4_to_h2x2(u_c.x, xv2);
        fp8x4_to_h2x2(u_c.y, xv2 + 2);
        float p = 0.0f;
        #pragma unroll
        for (int i = 0; i < 4; ++i) {
            h2 e  = xv2[i] + xr2[i];
            h2 el = __builtin_elementwise_max(e, e * (_Float16)NEG);
            p = __builtin_amdgcn_fdot2(el, at2[i], p, false);
        }
        p += __shfl_xor(p, 1, 64);
        p += __shfl_xor(p, 2, 64);
        float wgt = val_c ? exp2f(p) : 0.0f;
        lsum += wgt;
        _Float16 wh = (_Float16)wgt;
        h2 w2 = {wh, wh};
        #pragma unroll
        for (int i = 0; i < 4; ++i) acch[i] += w2 * xv2[i];
        u_c = u_n; u_n = u_2;
        val_c = val_n; val_n = val_2;
        val_2 = val_3; src_2 = src_3;
    }
    float acc[8];
    #pragma unroll
    for (int i = 0; i < 4; ++i) {
        acc[2 * i]     = (float)acch[i][0];
        acc[2 * i + 1] = (float)acch[i][1];
    }
    #pragma unroll
    for (int i = 0; i < 8; ++i) {
        acc[i] += __shfl_xor(acc[i], 16, 64);
        acc[i] += __shfl_xor(acc[i], 32, 64);
    }
    lsum += __shfl_xor(lsum, 16, 64);
    lsum += __shfl_xor(lsum, 32, 64);
    float inv = 1.0f / lsum;
    const unsigned short* xinrow = L0 ? (x3bf + (size_t)tyn * D) : (xin + (size_t)node * D);
    float xi[8];
    {
        uint4 u = *(const uint4*)(xinrow + cb);
        float2 a = bf2_to_f2(u.x), b = bf2_to_f2(u.y), c = bf2_to_f2(u.z), d = bf2_to_f2(u.w);
        xi[0]=a.x; xi[1]=a.y; xi[2]=b.x; xi[3]=b.y; xi[4]=c.x; xi[5]=c.y; xi[6]=d.x; xi[7]=d.y;
    }
    float4 gb0 = *(const float4*)(gbias + cb);
    float4 gb1 = *(const float4*)(gbias + cb + 4);
    float gb[8] = {gb0.x, gb0.y, gb0.z, gb0.w, gb1.x, gb1.y, gb1.z, gb1.w};
    float v[8];
    #pragma unroll
    for (int i = 0; i < 8; ++i) v[i] = fmaf(acc[i], inv, gb[i] + xi[i]);
    float s = 0.0f, sq = 0.0f;
    #pragma unroll
    for (int i = 0; i < 8; ++i) { s += v[i]; sq = fmaf(v[i], v[i], sq); }
    #pragma unroll
    for (int off = 1; off < 16; off <<= 1) {
        s  += __shfl_xor(s, off, 64);
        sq += __shfl_xor(sq, off, 64);
    }
    float mu  = s * (1.0f / D);
    float var = sq * (1.0f / D) - mu * mu;
    float r   = rsqrtf(var + EPS);
    float4 lg0 = *(const float4*)(lng + cb);
    float4 lg1 = *(const float4*)(lng + cb + 4);
    float4 lb0 = *(const float4*)(lnb + cb);
    float4 lb1 = *(const float4*)(lnb + cb + 4);
    float lg[8] = {lg0.x, lg0.y, lg0.z, lg0.w, lg1.x, lg1.y, lg1.z, lg1.w};
    float lb[8] = {lb0.x, lb0.y, lb0.z, lb0.w, lb1.x, lb1.y, lb1.z, lb1.w};
    float o[8];
    #pragma unroll
    for (int i = 0; i < 8; ++i) o[i] = fmaxf((v[i] - mu) * r * lg[i] + lb[i], 0.0f);
    if (g == 0) {
        if (xout_f32) {
            *(float4*)(xout_f32 + (size_t)node * D + cb)     = make_float4(o[0], o[1], o[2], o[3]);
            *(float4*)(xout_f32 + (size_t)node * D + cb + 4) = make_float4(o[4], o[5], o[6], o[7]);
        } else {
            unsigned int p0 = (unsigned int)f2bf(o[0]) | ((unsigned int)f2bf(o[1]) << 16);
            unsigned int p1 = (unsigned int)f2bf(o[2]) | ((unsigned int)f2bf(o[3]) << 16);
            unsigned int p2 = (unsigned int)f2bf(o[4]) | ((unsigned int)f2bf(o[5]) << 16);
            unsigned int p3 = (unsigned int)f2bf(o[6]) | ((unsigned int)f2bf(o[7]) << 16);
            *(uint4*)(xout_bf + (size_t)node * D + cb) = make_uint4(p0, p1, p2, p3);
        }
    }
}

// ---------------------------------------------------------------------------
extern "C" void kernel_launch(void* const* d_in, const int* in_sizes, int n_in,
                              void* d_out, int out_size, void* d_ws, size_t ws_size,
                              hipStream_t stream) {
    const int*   node_types = (const int*)d_in[0];
    const int*   edge_index = (const int*)d_in[1];
    const float* emb        = (const float*)d_in[2];
    const float* projW      = (const float*)d_in[3];
    const float* projb      = (const float*)d_in[4];
    const float* projg      = (const float*)d_in[5];
    const float* projbeta   = (const float*)d_in[6];
    const float* Wl         = (const float*)d_in[7];
    const float* bl         = (const float*)d_in[8];
    const float* Wr         = (const float*)d_in[9];
    const float* br         = (const float*)d_in[10];
    const float* att        = (const float*)d_in[11];
    const float* gbias      = (const float*)d_in[12];
    const float* lng        = (const float*)d_in[13];
    const float* lnb        = (const float*)d_in[14];
    float* out = (float*)d_out;

    int n = in_sizes[0];
    int e = in_sizes[1] / 2;
    const int* srcs = edge_index;
    const int* dsts = edge_index + e;

    char* p = (char*)d_ws;
    auto carve = [&](size_t bytes) {
        char* q = p;
        p += (bytes + 255) & ~(size_t)255;
        return q;
    };
    int*   deg     = (int*)carve((size_t)n * 4);
    int*   offs    = (int*)carve((size_t)(n + 1) * 4);
    int*   cursor  = (int*)carve((size_t)n * 4);
    int*   bsum    = (int*)carve(256 * 4);
    int*   csr_src = (int*)carve((size_t)(e + n) * 4);
    unsigned short* xbuf = (unsigned short*)carve((size_t)n * D * 2);
    unsigned char*  xlb  = (unsigned char*)carve((size_t)n * D);       // fp8
    unsigned short* xrb  = (unsigned short*)carve((size_t)n * D * 2);  // fp16
    unsigned short* wt   = (unsigned short*)carve((size_t)NLAYER * 2 * D * D * 2);
    unsigned short* x3bf = (unsigned short*)carve(3 * D * 2);
    unsigned char*  xl3  = (unsigned char*)carve(3 * D);
    unsigned short* xr3  = (unsigned short*)carve(3 * D * 2);

    int nb = (n + 255) / 256;
    int nbE = (e + 255) / 256;
    int ntiles = (n + 63) / 64;
    int nscat  = (e + n + 255) / 256;

    hipMemsetAsync(deg, 0, (size_t)n * 4, stream);

    // ---- setup: wt transpose | count_deg | proj3 (3-row x/xl0/xr0) ----
    setup_kernel<<<512 + nbE + 1, 256, 0, stream>>>(
        emb, projW, projb, projg, projbeta,
        Wl, Wr, bl, br, wt, dsts, deg, e,
        x3bf, xl3, xr3, nbE);

    // ---- CSR offsets + scatter (type-packed) ----
    scan_blocks_kernel<<<nb, 256, 0, stream>>>(deg, offs, bsum, n);
    scan_add_kernel<<<nb, 256, 0, stream>>>(offs, bsum, cursor, n, nb, e + n);
    scatter_kernel<<<nscat, 256, 0, stream>>>(srcs, dsts, node_types, e, n, cursor, csr_src);

    // ---- layer 0: agg straight from the 3-row tables (no GEMM needed) ----
    gat_agg_kernel<true><<<(n + 3) / 4, 256, 0, stream>>>(
        xlb, xrb, xbuf, xl3, xr3, x3bf, node_types, offs, csr_src,
        att, gbias, lng, lnb, xbuf, nullptr, n);

    // ---- layers 1..3 ----
    for (int layer = 1; layer < NLAYER; ++layer) {
        dual_gemm_mfma_kernel<<<ntiles, 256, 0, stream>>>(
            xbuf, wt + (size_t)layer * 2 * D * D,
            bl + (size_t)layer * D, br + (size_t)layer * D, xlb, xrb, n);
        bool last = (layer == NLAYER - 1);
        gat_agg_kernel<false><<<(n + 3) / 4, 256, 0, stream>>>(
            xlb, xrb, xbuf, xl3, xr3, x3bf, node_types, offs, csr_src,
            att + (size_t)layer * H * CH, gbias + (size_t)layer * D,
            lng + (size_t)layer * D, lnb + (size_t)layer * D,
            last ? (unsigned short*)nullptr : xbuf, last ? out : (float*)nullptr, n);
    }
}

// Round 15
// 328.124 us; speedup vs baseline: 1.2191x; 1.0763x over previous
//
#include <hip/hip_runtime.h>
#include <hip/hip_bf16.h>
#include <math.h>

#define D      128
#define NID    16
#define H      4
#define CH     32
#define NLAYER 4
#define EPS    1e-5f
#define NEG    0.2f
#define LOG2E  1.442695040888963f
#define CNTMASK 1023

typedef __attribute__((ext_vector_type(8))) short short8;
typedef __attribute__((ext_vector_type(4))) float floatx4;
typedef _Float16 h2 __attribute__((ext_vector_type(2)));
typedef float fx2 __attribute__((ext_vector_type(2)));

__device__ __forceinline__ float2 bf2_to_f2(unsigned int u) {
    float2 r;
    unsigned int lo = u << 16;
    unsigned int hi = u & 0xffff0000u;
    r.x = __uint_as_float(lo);
    r.y = __uint_as_float(hi);
    return r;
}

__device__ __forceinline__ unsigned short f2bf(float f) {
    __hip_bfloat16 h = __float2bfloat16(f);
    return *reinterpret_cast<unsigned short*>(&h);
}

__device__ __forceinline__ unsigned short f2h(float f) {
    _Float16 h = (_Float16)f;
    unsigned short u;
    __builtin_memcpy(&u, &h, 2);
    return u;
}

__device__ __forceinline__ h2 u2h2(unsigned int u) {
    h2 v;
    __builtin_memcpy(&v, &u, 4);
    return v;
}

__device__ __forceinline__ h2 pkrtz(float a, float b) {
    auto r = __builtin_amdgcn_cvt_pkrtz(a, b);
    h2 out;
    __builtin_memcpy(&out, &r, 4);
    return out;
}

// fp8 e4m3 (OCP on gfx950) encode of one float -> byte
__device__ __forceinline__ unsigned char f2fp8(float v) {
    int pk = __builtin_amdgcn_cvt_pk_fp8_f32(v, v, 0, false);
    return (unsigned char)(pk & 0xff);
}

// decode 4 fp8 bytes (one dword) -> 2x h2
__device__ __forceinline__ void fp8x4_to_h2x2(unsigned int w, h2* out) {
    fx2 f0 = __builtin_amdgcn_cvt_pk_f32_fp8((int)w, false);
    fx2 f1 = __builtin_amdgcn_cvt_pk_f32_fp8((int)w, true);
    out[0] = pkrtz(f0[0], f0[1]);
    out[1] = pkrtz(f1[0], f1[1]);
}

// ---------------------------------------------------------------------------
// KEY STRUCTURE (r13+r15): only 3 node types => x, xl0, xr0 each have 3
// distinct rows. r15: layer-0 AGGREGATION also collapses -- the edge logit
// depends only on (type_src,type_dst), 9 values/head. So L0 agg needs only
// per-type neighbor COUNTS (packed 3x10 bits in deg) and a 3x3xH exp(logit)
// table w9 -- no gather, no csr_src. csr_src is first needed by layer-1 agg,
// so the scatter folds into the GEMM-1 dispatch (overlap, r11 pattern).
// ---------------------------------------------------------------------------

__global__ __launch_bounds__(256) void scan_blocks_kernel(const int* __restrict__ deg, int* __restrict__ offs,
                                                          int* __restrict__ bsum, int n) {
    __shared__ int sw[8];
    int t = threadIdx.x;
    int i = blockIdx.x * 256 + t;
    int v = 0;
    if (i < n) {
        int d = deg[i];
        v = (d & CNTMASK) + ((d >> 10) & CNTMASK) + ((d >> 20) & CNTMASK) + 1;  // +1 self loop
    }
    int lane = t & 63, w = t >> 6;
    int x = v;
    #pragma unroll
    for (int off = 1; off < 64; off <<= 1) {
        int y = __shfl_up(x, off, 64);
        if (lane >= off) x += y;
    }
    if (lane == 63) sw[w] = x;
    __syncthreads();
    if (t == 0) {
        int s = 0;
        for (int k = 0; k < 4; ++k) { int tv = sw[k]; sw[k] = s; s += tv; }
        sw[4] = s;
    }
    __syncthreads();
    int excl = x - v + sw[w];
    if (i < n) offs[i] = excl;
    if (t == 255) bsum[blockIdx.x] = sw[4];
}

__global__ __launch_bounds__(256) void scan_add_kernel(int* __restrict__ offs, const int* __restrict__ bsum,
                                                       int* __restrict__ cursor, int n, int nb, int total) {
    __shared__ int sw[8];
    __shared__ int sS;
    int t = threadIdx.x;
    int bid = blockIdx.x;
    int v = (t < bid && t < nb) ? bsum[t] : 0;
    int lane = t & 63, w = t >> 6;
    #pragma unroll
    for (int off = 32; off > 0; off >>= 1) v += __shfl_xor(v, off, 64);
    if (lane == 0) sw[w] = v;
    __syncthreads();
    if (t == 0) sS = sw[0] + sw[1] + sw[2] + sw[3];
    __syncthreads();
    int S = sS;
    int i = bid * 256 + t;
    if (i < n) {
        int o = offs[i] + S;
        offs[i] = o;
        cursor[i] = o;
    }
    if (i == 0) offs[n] = total;
}

// ---------------------------------------------------------------------------
// Setup: [0,512) W->bf16 W^T; [512,512+nbE) typed count_deg
// (deg[dst] += 1<<(10*ty_src)); [last block] proj3: 3 rows of x (bf16),
// xl0/xr0 (f32), and the 9-logit exp table w9[tyd][tys][h].
// ---------------------------------------------------------------------------
__global__ __launch_bounds__(256) void setup_kernel(
    const float* __restrict__ emb,
    const float* __restrict__ W, const float* __restrict__ pb,
    const float* __restrict__ pg, const float* __restrict__ pbeta,
    const float* __restrict__ Wl, const float* __restrict__ Wr,
    const float* __restrict__ bl, const float* __restrict__ br,
    const float* __restrict__ att,
    unsigned short* __restrict__ wt,
    const int* __restrict__ srcs, const int* __restrict__ dsts,
    const int* __restrict__ types, int* __restrict__ deg, int e,
    unsigned short* __restrict__ x3bf, float* __restrict__ xl3f,
    float* __restrict__ w9,
    int nbE) {
    __shared__ float sbuf[2048];         // p3|x3s|red|xlf|xrf
    __shared__ float semb[3 * NID];
    int blk = blockIdx.x;
    int t = threadIdx.x;
    if (blk < 512) {
        int idx = blk * 256 + t;         // L*2*D*D = 131072
        int k    = idx & (D - 1);
        int nrow = (idx >> 7) & (D - 1);
        int s    = (idx >> 14) & 1;
        int l    = idx >> 15;
        const float* Wm = s ? Wr : Wl;
        wt[idx] = f2bf(Wm[(size_t)l * D * D + (size_t)k * D + nrow]);
    } else if (blk < 512 + nbE) {
        int i = (blk - 512) * 256 + t;
        if (i < e) {
            int ty = types[srcs[i]];
            atomicAdd(&deg[dsts[i]], 1 << (10 * ty));   // typed count
        }
    } else {
        // ---- proj3 ----
        float* p3  = sbuf;               // [3][128]
        float* x3s = sbuf + 384;         // [3][128] bf16-rounded
        float* red = sbuf + 768;         // [4]
        float* xlf = sbuf + 772;         // [3][128]
        float* xrf = sbuf + 1156;        // [3][128]
        for (int i = t; i < 3 * NID; i += 256) semb[i] = emb[i];
        __syncthreads();
        int c = t;
        if (c < D) {
            float wcol[NID];
            #pragma unroll
            for (int k = 0; k < NID; ++k) wcol[k] = W[k * D + c];
            float bc = pb[c];
            #pragma unroll
            for (int ty = 0; ty < 3; ++ty) {
                float a = bc;
                #pragma unroll
                for (int k = 0; k < NID; ++k) a = fmaf(semb[ty * NID + k], wcol[k], a);
                p3[ty * D + c] = a;
            }
        }
        __syncthreads();
        #pragma unroll 1
        for (int ty = 0; ty < 3; ++ty) {
            float v = (c < D) ? p3[ty * D + c] : 0.0f;
            float s = v, sq = v * v;
            #pragma unroll
            for (int off = 1; off < 64; off <<= 1) {
                s  += __shfl_xor(s, off, 64);
                sq += __shfl_xor(sq, off, 64);
            }
            if ((t & 63) == 0 && t < 128) { red[(t >> 6) * 2] = s; red[(t >> 6) * 2 + 1] = sq; }
            __syncthreads();
            float S = red[0] + red[2], SQ = red[1] + red[3];
            float mu = S * (1.0f / D), var = SQ * (1.0f / D) - mu * mu;
            float r = rsqrtf(var + EPS);
            if (c < D) {
                float o = fmaxf((p3[ty * D + c] - mu) * r * pg[c] + pbeta[c], 0.0f);
                unsigned short bfv = f2bf(o);
                x3s[ty * D + c] = __uint_as_float((unsigned int)bfv << 16);
                x3bf[ty * D + c] = bfv;
            }
            __syncthreads();
        }
        // xl0 / xr0 in f32
        if (c < D) {
            #pragma unroll 1
            for (int ty = 0; ty < 3; ++ty) {
                float al = bl[c], ar = br[c];
                for (int k = 0; k < D; ++k) {
                    float xv = x3s[ty * D + k];
                    al = fmaf(xv, Wl[(size_t)k * D + c], al);
                    ar = fmaf(xv, Wr[(size_t)k * D + c], ar);
                }
                xlf[ty * D + c] = al;
                xrf[ty * D + c] = ar;
                xl3f[ty * D + c] = al;
            }
        }
        __syncthreads();
        // w9[tyd][tys][h] = exp(att_h . leaky(xl[tys]+xr[tyd]))
        if (c < D) {
            float av = att[c];
            int h = c >> 5;
            #pragma unroll 1
            for (int tyd = 0; tyd < 3; ++tyd) {
                #pragma unroll 1
                for (int tys = 0; tys < 3; ++tys) {
                    float ev = xlf[tys * D + c] + xrf[tyd * D + c];
                    ev = fmaxf(ev, NEG * ev);
                    float p = av * ev;
                    #pragma unroll
                    for (int off = 1; off < 32; off <<= 1) p += __shfl_xor(p, off, 32);
                    if ((c & 31) == 0) w9[(tyd * 3 + tys) * H + h] = exp2f(p * LOG2E);
                }
            }
        }
    }
}

// ---------------------------------------------------------------------------
// Layer-0 aggregation, DENSE: per node only the typed neighbor counts are
// needed. out = LN( (Sum cnt_ty*w*xl3f[ty]) / (Sum cnt_ty*w) + gbias + x3 ).
// Grid-stride (2048 blocks), no LDS, f32 math. ~13MB traffic total.
// ---------------------------------------------------------------------------
__global__ __launch_bounds__(256) void gat_l0_dense_kernel(
    const int* __restrict__ deg, const int* __restrict__ types,
    const float* __restrict__ w9, const float* __restrict__ xl3f,
    const unsigned short* __restrict__ x3bf,
    const float* __restrict__ gbias,
    const float* __restrict__ lng, const float* __restrict__ lnb,
    unsigned short* __restrict__ xout, int n, int ngrp) {
    int t = threadIdx.x;
    int lane = t & 63, w = t >> 6;
    int c0 = 2 * lane;
    int h = c0 >> 5;
    for (int grp = blockIdx.x; grp < ngrp; grp += gridDim.x) {
        int node = grp * 4 + w;
        if (node >= n) continue;
        int tyn = types[node];
        int d = deg[node];
        float cnt[3];
        cnt[0] = (float)(d & CNTMASK);
        cnt[1] = (float)((d >> 10) & CNTMASK);
        cnt[2] = (float)((d >> 20) & CNTMASK);
        cnt[tyn] += 1.0f;                // self loop
        float cw0 = cnt[0] * w9[(tyn * 3 + 0) * H + h];
        float cw1 = cnt[1] * w9[(tyn * 3 + 1) * H + h];
        float cw2 = cnt[2] * w9[(tyn * 3 + 2) * H + h];
        float inv = 1.0f / (cw0 + cw1 + cw2);
        float n0 = cw0 * xl3f[0 * D + c0] + cw1 * xl3f[1 * D + c0] + cw2 * xl3f[2 * D + c0];
        float n1 = cw0 * xl3f[0 * D + c0 + 1] + cw1 * xl3f[1 * D + c0 + 1] + cw2 * xl3f[2 * D + c0 + 1];
        float2 xi = bf2_to_f2(*(const unsigned int*)(x3bf + (size_t)tyn * D + c0));
        float v0 = fmaf(n0, inv, gbias[c0]     + xi.x);
        float v1 = fmaf(n1, inv, gbias[c0 + 1] + xi.y);
        float s = v0 + v1, sq = v0 * v0 + v1 * v1;
        #pragma unroll
        for (int off = 1; off < 64; off <<= 1) {
            s  += __shfl_xor(s, off, 64);
            sq += __shfl_xor(sq, off, 64);
        }
        float mu  = s * (1.0f / D);
        float var = sq * (1.0f / D) - mu * mu;
        float r   = rsqrtf(var + EPS);
        v0 = fmaxf((v0 - mu) * r * lng[c0]     + lnb[c0],     0.0f);
        v1 = fmaxf((v1 - mu) * r * lng[c0 + 1] + lnb[c0 + 1], 0.0f);
        unsigned int packed = (unsigned int)f2bf(v0) | ((unsigned int)f2bf(v1) << 16);
        *(unsigned int*)(xout + (size_t)node * D + c0) = packed;
    }
}

// ---------------------------------------------------------------------------
// Dual GEMM via bf16 MFMA; bf16 in, fp8 xl / fp16 xr out. Layer 1 only:
// extra blocks past ntiles run the CSR scatter (first consumer is L1 agg).
// ---------------------------------------------------------------------------
__global__ __launch_bounds__(256) void dual_gemm_mfma_kernel(
    const unsigned short* __restrict__ x, const unsigned short* __restrict__ wt,
    const float* __restrict__ bl, const float* __restrict__ br,
    unsigned char* __restrict__ xl, unsigned short* __restrict__ xr, int n,
    int ntiles,
    const int* __restrict__ srcs, const int* __restrict__ dsts, int e,
    int* __restrict__ cursor, int* __restrict__ csr_src) {
    __shared__ __align__(16) unsigned short sa[64 * 136];
    int t = threadIdx.x;
    if (blockIdx.x >= ntiles) {
        // ---- scatter blocks (layer 1 only): dst-sorted CSR, self loops ----
        int i = (blockIdx.x - ntiles) * 256 + t;
        if (i < e) {
            int pos = atomicAdd(&cursor[dsts[i]], 1);
            csr_src[pos] = srcs[i];
        } else if (i < e + n) {
            int node = i - e;
            int pos = atomicAdd(&cursor[node], 1);
            csr_src[pos] = node;  // self loop
        }
        return;
    }
    int nbase = blockIdx.x * 64;
    int rows = n - nbase; if (rows > 64) rows = 64;
    int lane = t & 63, w = t >> 6;
    int L = lane & 15, q = lane >> 4;
    int s  = w >> 1;
    int n0 = (w & 1) * 64;
    const unsigned short* wb = wt + ((size_t)s * D + n0) * D;
    short8 b[4][4];
    #pragma unroll
    for (int kk = 0; kk < 4; ++kk)
        #pragma unroll
        for (int ni = 0; ni < 4; ++ni)
            b[kk][ni] = *(const short8*)(wb + (size_t)(ni * 16 + L) * D + kk * 32 + q * 8);
    {
        int r   = t >> 2;
        int seg = t & 3;
        uint4* drow = (uint4*)(sa + r * 136 + seg * 32);
        if (r < rows) {
            const uint4* srow = (const uint4*)(x + (size_t)(nbase + r) * D + seg * 32);
            drow[0] = srow[0]; drow[1] = srow[1]; drow[2] = srow[2]; drow[3] = srow[3];
        } else {
            uint4 z = make_uint4(0, 0, 0, 0);
            drow[0] = z; drow[1] = z; drow[2] = z; drow[3] = z;
        }
    }
    __syncthreads();
    floatx4 acc[4][4];
    #pragma unroll
    for (int mi = 0; mi < 4; ++mi)
        #pragma unroll
        for (int ni = 0; ni < 4; ++ni)
            acc[mi][ni] = (floatx4){0.0f, 0.0f, 0.0f, 0.0f};
    #pragma unroll
    for (int kk = 0; kk < 4; ++kk) {
        int ko = kk * 32 + q * 8;
        short8 a[4];
        #pragma unroll
        for (int mi = 0; mi < 4; ++mi)
            a[mi] = *(const short8*)(sa + (mi * 16 + L) * 136 + ko);
        #pragma unroll
        for (int mi = 0; mi < 4; ++mi)
            #pragma unroll
            for (int ni = 0; ni < 4; ++ni)
                acc[mi][ni] = __builtin_amdgcn_mfma_f32_16x16x32_bf16(a[mi], b[kk][ni], acc[mi][ni], 0, 0, 0);
    }
    const float* bias = s ? br : bl;
    // pass 0: xl fp8
    __syncthreads();
    if (s == 0) {
        unsigned char* sb = (unsigned char*)sa;
        #pragma unroll
        for (int ni = 0; ni < 4; ++ni) {
            int col = n0 + ni * 16 + L;
            float bv = bias[col];
            #pragma unroll
            for (int mi = 0; mi < 4; ++mi) {
                #pragma unroll
                for (int r = 0; r < 4; ++r) {
                    int row = mi * 16 + q * 4 + r;
                    sb[row * 272 + col] = f2fp8(acc[mi][ni][r] + bv);
                }
            }
        }
    }
    __syncthreads();
    {
        unsigned char* sb = (unsigned char*)sa;
        #pragma unroll
        for (int c = 0; c < 2; ++c) {
            int chunk = c * 256 + t;
            int row   = chunk >> 3;
            int off   = (chunk & 7) * 16;
            if (row < rows) {
                uint4 v = *(const uint4*)(sb + row * 272 + off);
                *(uint4*)(xl + (size_t)(nbase + row) * D + off) = v;
            }
        }
    }
    // pass 1: xr fp16
    __syncthreads();
    if (s == 1) {
        #pragma unroll
        for (int ni = 0; ni < 4; ++ni) {
            int col = n0 + ni * 16 + L;
            float bv = bias[col];
            #pragma unroll
            for (int mi = 0; mi < 4; ++mi) {
                #pragma unroll
                for (int r = 0; r < 4; ++r) {
                    int row = mi * 16 + q * 4 + r;
                    sa[row * 136 + col] = f2h(acc[mi][ni][r] + bv);
                }
            }
        }
    }
    __syncthreads();
    #pragma unroll
    for (int c = 0; c < 4; ++c) {
        int chunk = c * 256 + t;
        int row   = chunk >> 4;
        int off   = (chunk & 15) * 8;
        if (row < rows) {
            short8 v = *(const short8*)(sa + row * 136 + off);
            *(short8*)(xr + (size_t)(nbase + row) * D + off) = v;
        }
    }
}

// ---------------------------------------------------------------------------
// Fused GATv2 aggregation, layers 1-3: fp8 xl gather, fp16 packed MLP +
// pk_fma acc, 2-deep pipeline. att pre-scaled by log2(e) -> bare exp2f.
// ---------------------------------------------------------------------------
__global__ __launch_bounds__(256) void gat_agg_kernel(
    const unsigned char* __restrict__ xl, const unsigned short* __restrict__ xr,
    const unsigned short* __restrict__ xin,
    const int* __restrict__ offs, const int* __restrict__ csr_src,
    const float* __restrict__ att,
    const float* __restrict__ gbias,
    const float* __restrict__ lng, const float* __restrict__ lnb,
    unsigned short* __restrict__ xout_bf, float* __restrict__ xout_f32, int n) {
    int t = threadIdx.x;
    int lane = t & 63, w = t >> 6;
    int node = blockIdx.x * 4 + w;
    if (node >= n) return;
    int g  = lane >> 4;
    int l  = lane & 15;
    int cb = l * 8;
    h2 xr2[4], at2[4];
    {
        uint4 u = *(const uint4*)(xr + (size_t)node * D + cb);
        xr2[0] = u2h2(u.x); xr2[1] = u2h2(u.y); xr2[2] = u2h2(u.z); xr2[3] = u2h2(u.w);
        float4 t0 = *(const float4*)(att + cb);
        float4 t1 = *(const float4*)(att + cb + 4);
        at2[0] = (h2){(_Float16)(t0.x * LOG2E), (_Float16)(t0.y * LOG2E)};
        at2[1] = (h2){(_Float16)(t0.z * LOG2E), (_Float16)(t0.w * LOG2E)};
        at2[2] = (h2){(_Float16)(t1.x * LOG2E), (_Float16)(t1.y * LOG2E)};
        at2[3] = (h2){(_Float16)(t1.z * LOG2E), (_Float16)(t1.w * LOG2E)};
    }
    h2 acch[4];
    #pragma unroll
    for (int i = 0; i < 4; ++i) acch[i] = (h2){(_Float16)0.0f, (_Float16)0.0f};
    float lsum = 0.0f;
    int s0 = offs[node], s1 = offs[node + 1];
    int j0 = s0 + g;
    bool val_c = j0 < s1;
    int src_c = csr_src[val_c ? j0 : s0];
    uint2 u_c = *(const uint2*)(xl + (size_t)src_c * D + cb);
    int j1 = j0 + 4;
    bool val_n = j1 < s1;
    int src_n = csr_src[val_n ? j1 : s0];
    uint2 u_n = *(const uint2*)(xl + (size_t)src_n * D + cb);
    int j2 = j0 + 8;
    bool val_2 = j2 < s1;
    int src_2 = csr_src[val_2 ? j2 : s0];
    for (int j = s0; j < s1; j += 4) {
        uint2 u_2 = *(const uint2*)(xl + (size_t)src_2 * D + cb);
        int j3 = j + 12 + g;
        bool val_3 = j3 < s1;
        int src_3 = csr_src[val_3 ? j3 : s0];
        h2 xv2[4];
        fp8x4_to_h2x2(u_c.x, xv2);
        fp8x4_to_h2x2(u_c.y, xv2 + 2);
        float p = 0.0f;
        #pragma unroll
        for (int i = 0; i < 4; ++i) {
            h2 e  = xv2[i] + xr2[i];
            h2 el = __builtin_elementwise_max(e, e * (_Float16)NEG);
            p = __builtin_amdgcn_fdot2(el, at2[i], p, false);
        }
        p += __shfl_xor(p, 1, 64);
        p += __shfl_xor(p, 2, 64);
        float wgt = val_c ? exp2f(p) : 0.0f;
        lsum += wgt;
        _Float16 wh = (_Float16)wgt;
        h2 w2 = {wh, wh};
        #pragma unroll
        for (int i = 0; i < 4; ++i) acch[i] += w2 * xv2[i];
        u_c = u_n; u_n = u_2;
        val_c = val_n; val_n = val_2;
        val_2 = val_3; src_2 = src_3;
    }
    float acc[8];
    #pragma unroll
    for (int i = 0; i < 4; ++i) {
        acc[2 * i]     = (float)acch[i][0];
        acc[2 * i + 1] = (float)acch[i][1];
    }
    #pragma unroll
    for (int i = 0; i < 8; ++i) {
        acc[i] += __shfl_xor(acc[i], 16, 64);
        acc[i] += __shfl_xor(acc[i], 32, 64);
    }
    lsum += __shfl_xor(lsum, 16, 64);
    lsum += __shfl_xor(lsum, 32, 64);
    float inv = 1.0f / lsum;
    float xi[8];
    {
        uint4 u = *(const uint4*)(xin + (size_t)node * D + cb);
        float2 a = bf2_to_f2(u.x), b = bf2_to_f2(u.y), c = bf2_to_f2(u.z), d = bf2_to_f2(u.w);
        xi[0]=a.x; xi[1]=a.y; xi[2]=b.x; xi[3]=b.y; xi[4]=c.x; xi[5]=c.y; xi[6]=d.x; xi[7]=d.y;
    }
    float4 gb0 = *(const float4*)(gbias + cb);
    float4 gb1 = *(const float4*)(gbias + cb + 4);
    float gb[8] = {gb0.x, gb0.y, gb0.z, gb0.w, gb1.x, gb1.y, gb1.z, gb1.w};
    float v[8];
    #pragma unroll
    for (int i = 0; i < 8; ++i) v[i] = fmaf(acc[i], inv, gb[i] + xi[i]);
    float s = 0.0f, sq = 0.0f;
    #pragma unroll
    for (int i = 0; i < 8; ++i) { s += v[i]; sq = fmaf(v[i], v[i], sq); }
    #pragma unroll
    for (int off = 1; off < 16; off <<= 1) {
        s  += __shfl_xor(s, off, 64);
        sq += __shfl_xor(sq, off, 64);
    }
    float mu  = s * (1.0f / D);
    float var = sq * (1.0f / D) - mu * mu;
    float r   = rsqrtf(var + EPS);
    float4 lg0 = *(const float4*)(lng + cb);
    float4 lg1 = *(const float4*)(lng + cb + 4);
    float4 lb0 = *(const float4*)(lnb + cb);
    float4 lb1 = *(const float4*)(lnb + cb + 4);
    float lg[8] = {lg0.x, lg0.y, lg0.z, lg0.w, lg1.x, lg1.y, lg1.z, lg1.w};
    float lb[8] = {lb0.x, lb0.y, lb0.z, lb0.w, lb1.x, lb1.y, lb1.z, lb1.w};
    float o[8];
    #pragma unroll
    for (int i = 0; i < 8; ++i) o[i] = fmaxf((v[i] - mu) * r * lg[i] + lb[i], 0.0f);
    if (g == 0) {
        if (xout_f32) {
            *(float4*)(xout_f32 + (size_t)node * D + cb)     = make_float4(o[0], o[1], o[2], o[3]);
            *(float4*)(xout_f32 + (size_t)node * D + cb + 4) = make_float4(o[4], o[5], o[6], o[7]);
        } else {
            unsigned int p0 = (unsigned int)f2bf(o[0]) | ((unsigned int)f2bf(o[1]) << 16);
            unsigned int p1 = (unsigned int)f2bf(o[2]) | ((unsigned int)f2bf(o[3]) << 16);
            unsigned int p2 = (unsigned int)f2bf(o[4]) | ((unsigned int)f2bf(o[5]) << 16);
            unsigned int p3 = (unsigned int)f2bf(o[6]) | ((unsigned int)f2bf(o[7]) << 16);
            *(uint4*)(xout_bf + (size_t)node * D + cb) = make_uint4(p0, p1, p2, p3);
        }
    }
}

// ---------------------------------------------------------------------------
extern "C" void kernel_launch(void* const* d_in, const int* in_sizes, int n_in,
                              void* d_out, int out_size, void* d_ws, size_t ws_size,
                              hipStream_t stream) {
    const int*   node_types = (const int*)d_in[0];
    const int*   edge_index = (const int*)d_in[1];
    const float* emb        = (const float*)d_in[2];
    const float* projW      = (const float*)d_in[3];
    const float* projb      = (const float*)d_in[4];
    const float* projg      = (const float*)d_in[5];
    const float* projbeta   = (const float*)d_in[6];
    const float* Wl         = (const float*)d_in[7];
    const float* bl         = (const float*)d_in[8];
    const float* Wr         = (const float*)d_in[9];
    const float* br         = (const float*)d_in[10];
    const float* att        = (const float*)d_in[11];
    const float* gbias      = (const float*)d_in[12];
    const float* lng        = (const float*)d_in[13];
    const float* lnb        = (const float*)d_in[14];
    float* out = (float*)d_out;

    int n = in_sizes[0];
    int e = in_sizes[1] / 2;
    const int* srcs = edge_index;
    const int* dsts = edge_index + e;

    char* p = (char*)d_ws;
    auto carve = [&](size_t bytes) {
        char* q = p;
        p += (bytes + 255) & ~(size_t)255;
        return q;
    };
    int*   deg     = (int*)carve((size_t)n * 4);
    int*   offs    = (int*)carve((size_t)(n + 1) * 4);
    int*   cursor  = (int*)carve((size_t)n * 4);
    int*   bsum    = (int*)carve(256 * 4);
    int*   csr_src = (int*)carve((size_t)(e + n) * 4);
    unsigned short* xbuf = (unsigned short*)carve((size_t)n * D * 2);
    unsigned char*  xlb  = (unsigned char*)carve((size_t)n * D);       // fp8
    unsigned short* xrb  = (unsigned short*)carve((size_t)n * D * 2);  // fp16
    unsigned short* wt   = (unsigned short*)carve((size_t)NLAYER * 2 * D * D * 2);
    unsigned short* x3bf = (unsigned short*)carve(3 * D * 2);
    float*          xl3f = (float*)carve(3 * D * 4);
    float*          w9   = (float*)carve(9 * H * 4);

    int nb = (n + 255) / 256;
    int nbE = (e + 255) / 256;
    int ntiles = (n + 63) / 64;
    int nscat  = (e + n + 255) / 256;
    int ngrp   = (n + 3) / 4;

    hipMemsetAsync(deg, 0, (size_t)n * 4, stream);

    // ---- setup: wt transpose | typed count_deg | proj3 (+w9 table) ----
    setup_kernel<<<512 + nbE + 1, 256, 0, stream>>>(
        emb, projW, projb, projg, projbeta,
        Wl, Wr, bl, br, att, wt, srcs, dsts, node_types, deg, e,
        x3bf, xl3f, w9, nbE);

    // ---- CSR offsets ----
    scan_blocks_kernel<<<nb, 256, 0, stream>>>(deg, offs, bsum, n);
    scan_add_kernel<<<nb, 256, 0, stream>>>(offs, bsum, cursor, n, nb, e + n);

    // ---- layer 0: dense typed-count aggregation (no gather, no csr) ----
    gat_l0_dense_kernel<<<2048, 256, 0, stream>>>(
        deg, node_types, w9, xl3f, x3bf,
        gbias, lng, lnb, xbuf, n, ngrp);

    // ---- layers 1..3; layer-1 GEMM dispatch also runs the CSR scatter ----
    for (int layer = 1; layer < NLAYER; ++layer) {
        int extra = (layer == 1) ? nscat : 0;
        dual_gemm_mfma_kernel<<<ntiles + extra, 256, 0, stream>>>(
            xbuf, wt + (size_t)layer * 2 * D * D,
            bl + (size_t)layer * D, br + (size_t)layer * D, xlb, xrb, n,
            ntiles, srcs, dsts, e, cursor, csr_src);
        bool last = (layer == NLAYER - 1);
        gat_agg_kernel<<<ngrp, 256, 0, stream>>>(
            xlb, xrb, xbuf, offs, csr_src,
            att + (size_t)layer * H * CH, gbias + (size_t)layer * D,
            lng + (size_t)layer * D, lnb + (size_t)layer * D,
            last ? (unsigned short*)nullptr : xbuf, last ? out : (float*)nullptr, n);
    }
}

// Round 16
// 327.817 us; speedup vs baseline: 1.2203x; 1.0009x over previous
//
#include <hip/hip_runtime.h>
#include <hip/hip_bf16.h>
#include <math.h>

#define D      128
#define NID    16
#define H      4
#define CH     32
#define NLAYER 4
#define EPS    1e-5f
#define NEG    0.2f
#define LOG2E  1.442695040888963f
#define CNTMASK 1023
#define NBUCK  128      // buckets by dst>>9 (98 used for N=50000)
#define BCAP   8192     // per-bucket capacity (mean 6122, +26 sigma)

typedef __attribute__((ext_vector_type(8))) short short8;
typedef __attribute__((ext_vector_type(4))) float floatx4;
typedef _Float16 h2 __attribute__((ext_vector_type(2)));
typedef float fx2 __attribute__((ext_vector_type(2)));

__device__ __forceinline__ float2 bf2_to_f2(unsigned int u) {
    float2 r;
    unsigned int lo = u << 16;
    unsigned int hi = u & 0xffff0000u;
    r.x = __uint_as_float(lo);
    r.y = __uint_as_float(hi);
    return r;
}

__device__ __forceinline__ unsigned short f2bf(float f) {
    __hip_bfloat16 h = __float2bfloat16(f);
    return *reinterpret_cast<unsigned short*>(&h);
}

__device__ __forceinline__ unsigned short f2h(float f) {
    _Float16 h = (_Float16)f;
    unsigned short u;
    __builtin_memcpy(&u, &h, 2);
    return u;
}

__device__ __forceinline__ h2 u2h2(unsigned int u) {
    h2 v;
    __builtin_memcpy(&v, &u, 4);
    return v;
}

__device__ __forceinline__ h2 pkrtz(float a, float b) {
    auto r = __builtin_amdgcn_cvt_pkrtz(a, b);
    h2 out;
    __builtin_memcpy(&out, &r, 4);
    return out;
}

// fp8 e4m3 (OCP on gfx950) encode of one float -> byte
__device__ __forceinline__ unsigned char f2fp8(float v) {
    int pk = __builtin_amdgcn_cvt_pk_fp8_f32(v, v, 0, false);
    return (unsigned char)(pk & 0xff);
}

// decode 4 fp8 bytes (one dword) -> 2x h2
__device__ __forceinline__ void fp8x4_to_h2x2(unsigned int w, h2* out) {
    fx2 f0 = __builtin_amdgcn_cvt_pk_f32_fp8((int)w, false);
    fx2 f1 = __builtin_amdgcn_cvt_pk_f32_fp8((int)w, true);
    out[0] = pkrtz(f0[0], f0[1]);
    out[1] = pkrtz(f1[0], f1[1]);
}

// ---------------------------------------------------------------------------
// STRUCTURE: 3 node types => x/xl0/xr0 have 3 rows; L0 agg = dense typed
// counts + 9-logit table (r14/r15). r16: the CSR scatter's ~50us was random
// 4B writes bouncing 64B lines across non-coherent XCD L2s (~15x write
// amplification, 39MB measured). Now 2-pass: setup bins edges into 98
// dst-range buckets (block-local LDS histogram -> contiguous same-XCD runs),
// then per-bucket blocks (fused into GEMM-1 dispatch) replay into a ~30KB
// XCD-local csr window. Amplification ~1x.
// ---------------------------------------------------------------------------

__global__ __launch_bounds__(256) void scan_blocks_kernel(const int* __restrict__ deg, int* __restrict__ offs,
                                                          int* __restrict__ bsum, int n) {
    __shared__ int sw[8];
    int t = threadIdx.x;
    int i = blockIdx.x * 256 + t;
    int v = 0;
    if (i < n) {
        int d = deg[i];
        v = (d & CNTMASK) + ((d >> 10) & CNTMASK) + ((d >> 20) & CNTMASK) + 1;  // +1 self loop
    }
    int lane = t & 63, w = t >> 6;
    int x = v;
    #pragma unroll
    for (int off = 1; off < 64; off <<= 1) {
        int y = __shfl_up(x, off, 64);
        if (lane >= off) x += y;
    }
    if (lane == 63) sw[w] = x;
    __syncthreads();
    if (t == 0) {
        int s = 0;
        for (int k = 0; k < 4; ++k) { int tv = sw[k]; sw[k] = s; s += tv; }
        sw[4] = s;
    }
    __syncthreads();
    int excl = x - v + sw[w];
    if (i < n) offs[i] = excl;
    if (t == 255) bsum[blockIdx.x] = sw[4];
}

__global__ __launch_bounds__(256) void scan_add_kernel(int* __restrict__ offs, const int* __restrict__ bsum,
                                                       int* __restrict__ cursor, int n, int nb, int total) {
    __shared__ int sw[8];
    __shared__ int sS;
    int t = threadIdx.x;
    int bid = blockIdx.x;
    int v = (t < bid && t < nb) ? bsum[t] : 0;
    int lane = t & 63, w = t >> 6;
    #pragma unroll
    for (int off = 32; off > 0; off >>= 1) v += __shfl_xor(v, off, 64);
    if (lane == 0) sw[w] = v;
    __syncthreads();
    if (t == 0) sS = sw[0] + sw[1] + sw[2] + sw[3];
    __syncthreads();
    int S = sS;
    int i = bid * 256 + t;
    if (i < n) {
        int o = offs[i] + S;
        offs[i] = o;
        cursor[i] = o;
    }
    if (i == 0) offs[n] = total;
}

// ---------------------------------------------------------------------------
// Setup: [0,512) W->bf16 W^T; [512,512+nbP1) pass-1 edge binning + typed
// count_deg (2048 edges/block); [last] proj3 (3-row x/xl0/xr0 + w9 table).
// ---------------------------------------------------------------------------
__global__ __launch_bounds__(256) void setup_kernel(
    const float* __restrict__ emb,
    const float* __restrict__ W, const float* __restrict__ pb,
    const float* __restrict__ pg, const float* __restrict__ pbeta,
    const float* __restrict__ Wl, const float* __restrict__ Wr,
    const float* __restrict__ bl, const float* __restrict__ br,
    const float* __restrict__ att,
    unsigned short* __restrict__ wt,
    const int* __restrict__ srcs, const int* __restrict__ dsts,
    const int* __restrict__ types, int* __restrict__ deg, int e,
    int* __restrict__ bcur, int* __restrict__ gbuck,
    int* __restrict__ ovfcnt, int* __restrict__ govf,
    unsigned short* __restrict__ x3bf, float* __restrict__ xl3f,
    float* __restrict__ w9,
    int nbP1) {
    __shared__ float sbuf[2048];         // p3|x3s|red|xlf|xrf  OR  pass1 hists
    __shared__ float semb[3 * NID];
    int blk = blockIdx.x;
    int t = threadIdx.x;
    if (blk < 512) {
        int idx = blk * 256 + t;         // L*2*D*D = 131072
        int k    = idx & (D - 1);
        int nrow = (idx >> 7) & (D - 1);
        int s    = (idx >> 14) & 1;
        int l    = idx >> 15;
        const float* Wm = s ? Wr : Wl;
        wt[idx] = f2bf(Wm[(size_t)l * D * D + (size_t)k * D + nrow]);
    } else if (blk < 512 + nbP1) {
        // ---- pass 1: typed count + bucket binning (2048 edges/block) ----
        int* hcnt  = (int*)sbuf;         // [128]
        int* hbase = hcnt + NBUCK;       // [128]
        int* hloc  = hbase + NBUCK;      // [128]
        if (t < NBUCK) { hcnt[t] = 0; hloc[t] = 0; }
        __syncthreads();
        int ebase = (blk - 512) * 2048;
        int my_src[8], my_dst[8], my_b[8];
        #pragma unroll
        for (int k = 0; k < 8; ++k) {
            int i = ebase + k * 256 + t;
            my_b[k] = -1;
            if (i < e) {
                int s = srcs[i], d = dsts[i];
                my_src[k] = s; my_dst[k] = d;
                int b = d >> 9;
                my_b[k] = b;
                atomicAdd(&hcnt[b], 1);
                int ty = types[s];
                atomicAdd(&deg[d], 1 << (10 * ty));   // typed count
            }
        }
        __syncthreads();
        if (t < NBUCK) hbase[t] = atomicAdd(&bcur[t], hcnt[t]);
        __syncthreads();
        #pragma unroll
        for (int k = 0; k < 8; ++k) {
            int b = my_b[k];
            if (b >= 0) {
                int off = atomicAdd(&hloc[b], 1);
                int pos = hbase[b] + off;
                if (pos < BCAP) {
                    *(int2*)&gbuck[((size_t)b * BCAP + pos) * 2] = make_int2(my_src[k], my_dst[k]);
                } else {
                    int op = atomicAdd(ovfcnt, 1);
                    *(int2*)&govf[(size_t)op * 2] = make_int2(my_src[k], my_dst[k]);
                }
            }
        }
    } else {
        // ---- proj3 ----
        float* p3  = sbuf;               // [3][128]
        float* x3s = sbuf + 384;         // [3][128] bf16-rounded
        float* red = sbuf + 768;         // [4]
        float* xlf = sbuf + 772;         // [3][128]
        float* xrf = sbuf + 1156;        // [3][128]
        for (int i = t; i < 3 * NID; i += 256) semb[i] = emb[i];
        __syncthreads();
        int c = t;
        if (c < D) {
            float wcol[NID];
            #pragma unroll
            for (int k = 0; k < NID; ++k) wcol[k] = W[k * D + c];
            float bc = pb[c];
            #pragma unroll
            for (int ty = 0; ty < 3; ++ty) {
                float a = bc;
                #pragma unroll
                for (int k = 0; k < NID; ++k) a = fmaf(semb[ty * NID + k], wcol[k], a);
                p3[ty * D + c] = a;
            }
        }
        __syncthreads();
        #pragma unroll 1
        for (int ty = 0; ty < 3; ++ty) {
            float v = (c < D) ? p3[ty * D + c] : 0.0f;
            float s = v, sq = v * v;
            #pragma unroll
            for (int off = 1; off < 64; off <<= 1) {
                s  += __shfl_xor(s, off, 64);
                sq += __shfl_xor(sq, off, 64);
            }
            if ((t & 63) == 0 && t < 128) { red[(t >> 6) * 2] = s; red[(t >> 6) * 2 + 1] = sq; }
            __syncthreads();
            float S = red[0] + red[2], SQ = red[1] + red[3];
            float mu = S * (1.0f / D), var = SQ * (1.0f / D) - mu * mu;
            float r = rsqrtf(var + EPS);
            if (c < D) {
                float o = fmaxf((p3[ty * D + c] - mu) * r * pg[c] + pbeta[c], 0.0f);
                unsigned short bfv = f2bf(o);
                x3s[ty * D + c] = __uint_as_float((unsigned int)bfv << 16);
                x3bf[ty * D + c] = bfv;
            }
            __syncthreads();
        }
        // xl0 / xr0 in f32
        if (c < D) {
            #pragma unroll 1
            for (int ty = 0; ty < 3; ++ty) {
                float al = bl[c], ar = br[c];
                for (int k = 0; k < D; ++k) {
                    float xv = x3s[ty * D + k];
                    al = fmaf(xv, Wl[(size_t)k * D + c], al);
                    ar = fmaf(xv, Wr[(size_t)k * D + c], ar);
                }
                xlf[ty * D + c] = al;
                xrf[ty * D + c] = ar;
                xl3f[ty * D + c] = al;
            }
        }
        __syncthreads();
        // w9[tyd][tys][h] = exp(att_h . leaky(xl[tys]+xr[tyd]))
        if (c < D) {
            float av = att[c];
            int h = c >> 5;
            #pragma unroll 1
            for (int tyd = 0; tyd < 3; ++tyd) {
                #pragma unroll 1
                for (int tys = 0; tys < 3; ++tys) {
                    float ev = xlf[tys * D + c] + xrf[tyd * D + c];
                    ev = fmaxf(ev, NEG * ev);
                    float p = av * ev;
                    #pragma unroll
                    for (int off = 1; off < 32; off <<= 1) p += __shfl_xor(p, off, 32);
                    if ((c & 31) == 0) w9[(tyd * 3 + tys) * H + h] = exp2f(p * LOG2E);
                }
            }
        }
    }
}

// ---------------------------------------------------------------------------
// Layer-0 aggregation, DENSE (typed counts + w9 table), grid-stride.
// ---------------------------------------------------------------------------
__global__ __launch_bounds__(256) void gat_l0_dense_kernel(
    const int* __restrict__ deg, const int* __restrict__ types,
    const float* __restrict__ w9, const float* __restrict__ xl3f,
    const unsigned short* __restrict__ x3bf,
    const float* __restrict__ gbias,
    const float* __restrict__ lng, const float* __restrict__ lnb,
    unsigned short* __restrict__ xout, int n, int ngrp) {
    int t = threadIdx.x;
    int lane = t & 63, w = t >> 6;
    int c0 = 2 * lane;
    int h = c0 >> 5;
    for (int grp = blockIdx.x; grp < ngrp; grp += gridDim.x) {
        int node = grp * 4 + w;
        if (node >= n) continue;
        int tyn = types[node];
        int d = deg[node];
        float cnt[3];
        cnt[0] = (float)(d & CNTMASK);
        cnt[1] = (float)((d >> 10) & CNTMASK);
        cnt[2] = (float)((d >> 20) & CNTMASK);
        cnt[tyn] += 1.0f;                // self loop
        float cw0 = cnt[0] * w9[(tyn * 3 + 0) * H + h];
        float cw1 = cnt[1] * w9[(tyn * 3 + 1) * H + h];
        float cw2 = cnt[2] * w9[(tyn * 3 + 2) * H + h];
        float inv = 1.0f / (cw0 + cw1 + cw2);
        float n0 = cw0 * xl3f[0 * D + c0] + cw1 * xl3f[1 * D + c0] + cw2 * xl3f[2 * D + c0];
        float n1 = cw0 * xl3f[0 * D + c0 + 1] + cw1 * xl3f[1 * D + c0 + 1] + cw2 * xl3f[2 * D + c0 + 1];
        float2 xi = bf2_to_f2(*(const unsigned int*)(x3bf + (size_t)tyn * D + c0));
        float v0 = fmaf(n0, inv, gbias[c0]     + xi.x);
        float v1 = fmaf(n1, inv, gbias[c0 + 1] + xi.y);
        float s = v0 + v1, sq = v0 * v0 + v1 * v1;
        #pragma unroll
        for (int off = 1; off < 64; off <<= 1) {
            s  += __shfl_xor(s, off, 64);
            sq += __shfl_xor(sq, off, 64);
        }
        float mu  = s * (1.0f / D);
        float var = sq * (1.0f / D) - mu * mu;
        float r   = rsqrtf(var + EPS);
        v0 = fmaxf((v0 - mu) * r * lng[c0]     + lnb[c0],     0.0f);
        v1 = fmaxf((v1 - mu) * r * lng[c0 + 1] + lnb[c0 + 1], 0.0f);
        unsigned int packed = (unsigned int)f2bf(v0) | ((unsigned int)f2bf(v1) << 16);
        *(unsigned int*)(xout + (size_t)node * D + c0) = packed;
    }
}

// ---------------------------------------------------------------------------
// Dual GEMM via bf16 MFMA; bf16 in, fp8 xl / fp16 xr out. Layer 1 only:
// extra blocks run pass-2 scatter (per-bucket replay, XCD-local) +
// self loops + overflow.
// ---------------------------------------------------------------------------
__global__ __launch_bounds__(256) void dual_gemm_mfma_kernel(
    const unsigned short* __restrict__ x, const unsigned short* __restrict__ wt,
    const float* __restrict__ bl, const float* __restrict__ br,
    unsigned char* __restrict__ xl, unsigned short* __restrict__ xr, int n,
    int ntiles, int nself,
    const int* __restrict__ bcur, const int* __restrict__ gbuck,
    const int* __restrict__ ovfcnt, const int* __restrict__ govf,
    int* __restrict__ cursor, int* __restrict__ csr_src) {
    __shared__ __align__(16) unsigned short sa[64 * 136];
    int t = threadIdx.x;
    if (blockIdx.x >= ntiles) {
        int xb = blockIdx.x - ntiles;
        if (xb < NBUCK) {
            // ---- pass-2: replay bucket xb into its ~30KB csr window ----
            int cnt = bcur[xb]; if (cnt > BCAP) cnt = BCAP;
            const int* bp = gbuck + (size_t)xb * BCAP * 2;
            for (int i = t; i < cnt; i += 256) {
                int s = bp[2 * i], d = bp[2 * i + 1];
                int pos = atomicAdd(&cursor[d], 1);
                csr_src[pos] = s;
            }
        } else if (xb < NBUCK + nself) {
            // ---- self loops (node-range-local) ----
            int node = (xb - NBUCK) * 256 + t;
            if (node < n) {
                int pos = atomicAdd(&cursor[node], 1);
                csr_src[pos] = node;
            }
        } else {
            // ---- overflow edges (expected ~0) ----
            int cnt = *ovfcnt;
            for (int i = t; i < cnt; i += 256) {
                int s = govf[2 * i], d = govf[2 * i + 1];
                int pos = atomicAdd(&cursor[d], 1);
                csr_src[pos] = s;
            }
        }
        return;
    }
    int nbase = blockIdx.x * 64;
    int rows = n - nbase; if (rows > 64) rows = 64;
    int lane = t & 63, w = t >> 6;
    int L = lane & 15, q = lane >> 4;
    int s  = w >> 1;
    int n0 = (w & 1) * 64;
    const unsigned short* wb = wt + ((size_t)s * D + n0) * D;
    short8 b[4][4];
    #pragma unroll
    for (int kk = 0; kk < 4; ++kk)
        #pragma unroll
        for (int ni = 0; ni < 4; ++ni)
            b[kk][ni] = *(const short8*)(wb + (size_t)(ni * 16 + L) * D + kk * 32 + q * 8);
    {
        int r   = t >> 2;
        int seg = t & 3;
        uint4* drow = (uint4*)(sa + r * 136 + seg * 32);
        if (r < rows) {
            const uint4* srow = (const uint4*)(x + (size_t)(nbase + r) * D + seg * 32);
            drow[0] = srow[0]; drow[1] = srow[1]; drow[2] = srow[2]; drow[3] = srow[3];
        } else {
            uint4 z = make_uint4(0, 0, 0, 0);
            drow[0] = z; drow[1] = z; drow[2] = z; drow[3] = z;
        }
    }
    __syncthreads();
    floatx4 acc[4][4];
    #pragma unroll
    for (int mi = 0; mi < 4; ++mi)
        #pragma unroll
        for (int ni = 0; ni < 4; ++ni)
            acc[mi][ni] = (floatx4){0.0f, 0.0f, 0.0f, 0.0f};
    #pragma unroll
    for (int kk = 0; kk < 4; ++kk) {
        int ko = kk * 32 + q * 8;
        short8 a[4];
        #pragma unroll
        for (int mi = 0; mi < 4; ++mi)
            a[mi] = *(const short8*)(sa + (mi * 16 + L) * 136 + ko);
        #pragma unroll
        for (int mi = 0; mi < 4; ++mi)
            #pragma unroll
            for (int ni = 0; ni < 4; ++ni)
                acc[mi][ni] = __builtin_amdgcn_mfma_f32_16x16x32_bf16(a[mi], b[kk][ni], acc[mi][ni], 0, 0, 0);
    }
    const float* bias = s ? br : bl;
    // pass 0: xl fp8
    __syncthreads();
    if (s == 0) {
        unsigned char* sb = (unsigned char*)sa;
        #pragma unroll
        for (int ni = 0; ni < 4; ++ni) {
            int col = n0 + ni * 16 + L;
            float bv = bias[col];
            #pragma unroll
            for (int mi = 0; mi < 4; ++mi) {
                #pragma unroll
                for (int r = 0; r < 4; ++r) {
                    int row = mi * 16 + q * 4 + r;
                    sb[row * 272 + col] = f2fp8(acc[mi][ni][r] + bv);
                }
            }
        }
    }
    __syncthreads();
    {
        unsigned char* sb = (unsigned char*)sa;
        #pragma unroll
        for (int c = 0; c < 2; ++c) {
            int chunk = c * 256 + t;
            int row   = chunk >> 3;
            int off   = (chunk & 7) * 16;
            if (row < rows) {
                uint4 v = *(const uint4*)(sb + row * 272 + off);
                *(uint4*)(xl + (size_t)(nbase + row) * D + off) = v;
            }
        }
    }
    // pass 1: xr fp16
    __syncthreads();
    if (s == 1) {
        #pragma unroll
        for (int ni = 0; ni < 4; ++ni) {
            int col = n0 + ni * 16 + L;
            float bv = bias[col];
            #pragma unroll
            for (int mi = 0; mi < 4; ++mi) {
                #pragma unroll
                for (int r = 0; r < 4; ++r) {
                    int row = mi * 16 + q * 4 + r;
                    sa[row * 136 + col] = f2h(acc[mi][ni][r] + bv);
                }
            }
        }
    }
    __syncthreads();
    #pragma unroll
    for (int c = 0; c < 4; ++c) {
        int chunk = c * 256 + t;
        int row   = chunk >> 4;
        int off   = (chunk & 15) * 8;
        if (row < rows) {
            short8 v = *(const short8*)(sa + row * 136 + off);
            *(short8*)(xr + (size_t)(nbase + row) * D + off) = v;
        }
    }
}

// ---------------------------------------------------------------------------
// Fused GATv2 aggregation, layers 1-3: fp8 xl gather, fp16 packed MLP +
// pk_fma acc, 2-deep pipeline. att pre-scaled by log2(e) -> bare exp2f.
// ---------------------------------------------------------------------------
__global__ __launch_bounds__(256) void gat_agg_kernel(
    const unsigned char* __restrict__ xl, const unsigned short* __restrict__ xr,
    const unsigned short* __restrict__ xin,
    const int* __restrict__ offs, const int* __restrict__ csr_src,
    const float* __restrict__ att,
    const float* __restrict__ gbias,
    const float* __restrict__ lng, const float* __restrict__ lnb,
    unsigned short* __restrict__ xout_bf, float* __restrict__ xout_f32, int n) {
    int t = threadIdx.x;
    int lane = t & 63, w = t >> 6;
    int node = blockIdx.x * 4 + w;
    if (node >= n) return;
    int g  = lane >> 4;
    int l  = lane & 15;
    int cb = l * 8;
    h2 xr2[4], at2[4];
    {
        uint4 u = *(const uint4*)(xr + (size_t)node * D + cb);
        xr2[0] = u2h2(u.x); xr2[1] = u2h2(u.y); xr2[2] = u2h2(u.z); xr2[3] = u2h2(u.w);
        float4 t0 = *(const float4*)(att + cb);
        float4 t1 = *(const float4*)(att + cb + 4);
        at2[0] = (h2){(_Float16)(t0.x * LOG2E), (_Float16)(t0.y * LOG2E)};
        at2[1] = (h2){(_Float16)(t0.z * LOG2E), (_Float16)(t0.w * LOG2E)};
        at2[2] = (h2){(_Float16)(t1.x * LOG2E), (_Float16)(t1.y * LOG2E)};
        at2[3] = (h2){(_Float16)(t1.z * LOG2E), (_Float16)(t1.w * LOG2E)};
    }
    h2 acch[4];
    #pragma unroll
    for (int i = 0; i < 4; ++i) acch[i] = (h2){(_Float16)0.0f, (_Float16)0.0f};
    float lsum = 0.0f;
    int s0 = offs[node], s1 = offs[node + 1];
    int j0 = s0 + g;
    bool val_c = j0 < s1;
    int src_c = csr_src[val_c ? j0 : s0];
    uint2 u_c = *(const uint2*)(xl + (size_t)src_c * D + cb);
    int j1 = j0 + 4;
    bool val_n = j1 < s1;
    int src_n = csr_src[val_n ? j1 : s0];
    uint2 u_n = *(const uint2*)(xl + (size_t)src_n * D + cb);
    int j2 = j0 + 8;
    bool val_2 = j2 < s1;
    int src_2 = csr_src[val_2 ? j2 : s0];
    for (int j = s0; j < s1; j += 4) {
        uint2 u_2 = *(const uint2*)(xl + (size_t)src_2 * D + cb);
        int j3 = j + 12 + g;
        bool val_3 = j3 < s1;
        int src_3 = csr_src[val_3 ? j3 : s0];
        h2 xv2[4];
        fp8x4_to_h2x2(u_c.x, xv2);
        fp8x4_to_h2x2(u_c.y, xv2 + 2);
        float p = 0.0f;
        #pragma unroll
        for (int i = 0; i < 4; ++i) {
            h2 e  = xv2[i] + xr2[i];
            h2 el = __builtin_elementwise_max(e, e * (_Float16)NEG);
            p = __builtin_amdgcn_fdot2(el, at2[i], p, false);
        }
        p += __shfl_xor(p, 1, 64);
        p += __shfl_xor(p, 2, 64);
        float wgt = val_c ? exp2f(p) : 0.0f;
        lsum += wgt;
        _Float16 wh = (_Float16)wgt;
        h2 w2 = {wh, wh};
        #pragma unroll
        for (int i = 0; i < 4; ++i) acch[i] += w2 * xv2[i];
        u_c = u_n; u_n = u_2;
        val_c = val_n; val_n = val_2;
        val_2 = val_3; src_2 = src_3;
    }
    float acc[8];
    #pragma unroll
    for (int i = 0; i < 4; ++i) {
        acc[2 * i]     = (float)acch[i][0];
        acc[2 * i + 1] = (float)acch[i][1];
    }
    #pragma unroll
    for (int i = 0; i < 8; ++i) {
        acc[i] += __shfl_xor(acc[i], 16, 64);
        acc[i] += __shfl_xor(acc[i], 32, 64);
    }
    lsum += __shfl_xor(lsum, 16, 64);
    lsum += __shfl_xor(lsum, 32, 64);
    float inv = 1.0f / lsum;
    float xi[8];
    {
        uint4 u = *(const uint4*)(xin + (size_t)node * D + cb);
        float2 a = bf2_to_f2(u.x), b = bf2_to_f2(u.y), c = bf2_to_f2(u.z), d = bf2_to_f2(u.w);
        xi[0]=a.x; xi[1]=a.y; xi[2]=b.x; xi[3]=b.y; xi[4]=c.x; xi[5]=c.y; xi[6]=d.x; xi[7]=d.y;
    }
    float4 gb0 = *(const float4*)(gbias + cb);
    float4 gb1 = *(const float4*)(gbias + cb + 4);
    float gb[8] = {gb0.x, gb0.y, gb0.z, gb0.w, gb1.x, gb1.y, gb1.z, gb1.w};
    float v[8];
    #pragma unroll
    for (int i = 0; i < 8; ++i) v[i] = fmaf(acc[i], inv, gb[i] + xi[i]);
    float s = 0.0f, sq = 0.0f;
    #pragma unroll
    for (int i = 0; i < 8; ++i) { s += v[i]; sq = fmaf(v[i], v[i], sq); }
    #pragma unroll
    for (int off = 1; off < 16; off <<= 1) {
        s  += __shfl_xor(s, off, 64);
        sq += __shfl_xor(sq, off, 64);
    }
    float mu  = s * (1.0f / D);
    float var = sq * (1.0f / D) - mu * mu;
    float r   = rsqrtf(var + EPS);
    float4 lg0 = *(const float4*)(lng + cb);
    float4 lg1 = *(const float4*)(lng + cb + 4);
    float4 lb0 = *(const float4*)(lnb + cb);
    float4 lb1 = *(const float4*)(lnb + cb + 4);
    float lg[8] = {lg0.x, lg0.y, lg0.z, lg0.w, lg1.x, lg1.y, lg1.z, lg1.w};
    float lb[8] = {lb0.x, lb0.y, lb0.z, lb0.w, lb1.x, lb1.y, lb1.z, lb1.w};
    float o[8];
    #pragma unroll
    for (int i = 0; i < 8; ++i) o[i] = fmaxf((v[i] - mu) * r * lg[i] + lb[i], 0.0f);
    if (g == 0) {
        if (xout_f32) {
            *(float4*)(xout_f32 + (size_t)node * D + cb)     = make_float4(o[0], o[1], o[2], o[3]);
            *(float4*)(xout_f32 + (size_t)node * D + cb + 4) = make_float4(o[4], o[5], o[6], o[7]);
        } else {
            unsigned int p0 = (unsigned int)f2bf(o[0]) | ((unsigned int)f2bf(o[1]) << 16);
            unsigned int p1 = (unsigned int)f2bf(o[2]) | ((unsigned int)f2bf(o[3]) << 16);
            unsigned int p2 = (unsigned int)f2bf(o[4]) | ((unsigned int)f2bf(o[5]) << 16);
            unsigned int p3 = (unsigned int)f2bf(o[6]) | ((unsigned int)f2bf(o[7]) << 16);
            *(uint4*)(xout_bf + (size_t)node * D + cb) = make_uint4(p0, p1, p2, p3);
        }
    }
}

// ---------------------------------------------------------------------------
extern "C" void kernel_launch(void* const* d_in, const int* in_sizes, int n_in,
                              void* d_out, int out_size, void* d_ws, size_t ws_size,
                              hipStream_t stream) {
    const int*   node_types = (const int*)d_in[0];
    const int*   edge_index = (const int*)d_in[1];
    const float* emb        = (const float*)d_in[2];
    const float* projW      = (const float*)d_in[3];
    const float* projb      = (const float*)d_in[4];
    const float* projg      = (const float*)d_in[5];
    const float* projbeta   = (const float*)d_in[6];
    const float* Wl         = (const float*)d_in[7];
    const float* bl         = (const float*)d_in[8];
    const float* Wr         = (const float*)d_in[9];
    const float* br         = (const float*)d_in[10];
    const float* att        = (const float*)d_in[11];
    const float* gbias      = (const float*)d_in[12];
    const float* lng        = (const float*)d_in[13];
    const float* lnb        = (const float*)d_in[14];
    float* out = (float*)d_out;

    int n = in_sizes[0];
    int e = in_sizes[1] / 2;
    const int* srcs = edge_index;
    const int* dsts = edge_index + e;

    char* p = (char*)d_ws;
    auto carve = [&](size_t bytes) {
        char* q = p;
        p += (bytes + 255) & ~(size_t)255;
        return q;
    };
    int*   deg     = (int*)carve((size_t)n * 4);
    int*   offs    = (int*)carve((size_t)(n + 1) * 4);
    int*   cursor  = (int*)carve((size_t)n * 4);
    int*   bsum    = (int*)carve(256 * 4);
    int*   csr_src = (int*)carve((size_t)(e + n) * 4);
    unsigned short* xbuf = (unsigned short*)carve((size_t)n * D * 2);
    unsigned char*  xlb  = (unsigned char*)carve((size_t)n * D);       // fp8
    unsigned short* xrb  = (unsigned short*)carve((size_t)n * D * 2);  // fp16
    unsigned short* wt   = (unsigned short*)carve((size_t)NLAYER * 2 * D * D * 2);
    unsigned short* x3bf = (unsigned short*)carve(3 * D * 2);
    float*          xl3f = (float*)carve(3 * D * 4);
    float*          w9   = (float*)carve(9 * H * 4);
    int*   bstate  = (int*)carve(256 * 4);            // bcur[128] + ovfcnt
    int*   bcur    = bstate;
    int*   ovfcnt  = bstate + 128;
    int*   gbuck   = (int*)carve((size_t)NBUCK * BCAP * 8);
    int*   govf    = (int*)carve((size_t)e * 8);

    int nb = (n + 255) / 256;
    int nbP1 = (e + 2047) / 2048;
    int ntiles = (n + 63) / 64;
    int nself = (n + 255) / 256;
    int ngrp   = (n + 3) / 4;

    hipMemsetAsync(deg, 0, (size_t)n * 4, stream);
    hipMemsetAsync(bstate, 0, 256 * 4, stream);

    // ---- setup: wt transpose | pass-1 binning + typed count | proj3 ----
    setup_kernel<<<512 + nbP1 + 1, 256, 0, stream>>>(
        emb, projW, projb, projg, projbeta,
        Wl, Wr, bl, br, att, wt, srcs, dsts, node_types, deg, e,
        bcur, gbuck, ovfcnt, govf,
        x3bf, xl3f, w9, nbP1);

    // ---- CSR offsets ----
    scan_blocks_kernel<<<nb, 256, 0, stream>>>(deg, offs, bsum, n);
    scan_add_kernel<<<nb, 256, 0, stream>>>(offs, bsum, cursor, n, nb, e + n);

    // ---- layer 0: dense typed-count aggregation ----
    gat_l0_dense_kernel<<<2048, 256, 0, stream>>>(
        deg, node_types, w9, xl3f, x3bf,
        gbias, lng, lnb, xbuf, n, ngrp);

    // ---- layers 1..3; layer-1 GEMM dispatch also runs pass-2 scatter ----
    for (int layer = 1; layer < NLAYER; ++layer) {
        int extra = (layer == 1) ? (NBUCK + nself + 1) : 0;
        dual_gemm_mfma_kernel<<<ntiles + extra, 256, 0, stream>>>(
            xbuf, wt + (size_t)layer * 2 * D * D,
            bl + (size_t)layer * D, br + (size_t)layer * D, xlb, xrb, n,
            ntiles, nself, bcur, gbuck, ovfcnt, govf, cursor, csr_src);
        bool last = (layer == NLAYER - 1);
        gat_agg_kernel<<<ngrp, 256, 0, stream>>>(
            xlb, xrb, xbuf, offs, csr_src,
            att + (size_t)layer * H * CH, gbias + (size_t)layer * D,
            lng + (size_t)layer * D, lnb + (size_t)layer * D,
            last ? (unsigned short*)nullptr : xbuf, last ? out : (float*)nullptr, n);
    }
}